// Round 2
// baseline (1505.779 us; speedup 1.0000x reference)
//
#include <hip/hip_runtime.h>
#include <math.h>

#define HW 16384

// ---------------------------------------------------------------------------
// Weight prep (runs once per call, ~0.5 µs of traffic):
//  - deform weights w[o][c][k] -> wt[(c*9+k)][o]
//  - conv3x3 weights w[o][c][k] -> wt[c][ob][k][oi] (o = ob*4+oi, zero-pad o>=O)
//  - upconv weights w[o][ci][t] -> uw[ci][ob][oi][t]
// ---------------------------------------------------------------------------
__device__ inline float conv_tw(const float* __restrict__ src, int Cin, int O,
                                int Oq, int d) {
  int oi = d & 3;
  int k = (d >> 2) % 9;
  int rest = d / 36;
  int ob = rest % Oq;
  int c = rest / Oq;
  int o = ob * 4 + oi;
  return (o < O) ? src[((size_t)o * Cin + c) * 9 + k] : 0.f;
}

__global__ __launch_bounds__(256) void prep_kernel(
    const float* __restrict__ dl_w, const float* __restrict__ dr_w,
    const float* __restrict__ offl_w, const float* __restrict__ offr_w,
    const float* __restrict__ cv_w, const float* __restrict__ r11,
    const float* __restrict__ r12, const float* __restrict__ r21,
    const float* __restrict__ r22, const float* __restrict__ up_w,
    float* __restrict__ wtl, float* __restrict__ wtr,
    float* __restrict__ w_offl, float* __restrict__ w_offr,
    float* __restrict__ w_cv, float* __restrict__ w_r11,
    float* __restrict__ w_r12, float* __restrict__ w_r21,
    float* __restrict__ w_r22, float* __restrict__ upwt) {
  int d = blockIdx.x * 256 + threadIdx.x;
  const int S_def = 36864;   // 64*64*9
  const int S_off = 48384;   // 192*7*36
  const int S_cv = 110592;   // 192*16*36
  const int S_rb = 36864;    // 64*16*36
  const int S_up = 32768;    // 128*16*16
  if (d < S_def) { int r = d >> 6, o = d & 63; wtl[d] = dl_w[o * 576 + r]; return; }
  d -= S_def;
  if (d < S_def) { int r = d >> 6, o = d & 63; wtr[d] = dr_w[o * 576 + r]; return; }
  d -= S_def;
  if (d < S_off) { w_offl[d] = conv_tw(offl_w, 192, 27, 7, d); return; }
  d -= S_off;
  if (d < S_off) { w_offr[d] = conv_tw(offr_w, 192, 27, 7, d); return; }
  d -= S_off;
  if (d < S_cv) { w_cv[d] = conv_tw(cv_w, 192, 64, 16, d); return; }
  d -= S_cv;
  if (d < S_rb) { w_r11[d] = conv_tw(r11, 64, 64, 16, d); return; }
  d -= S_rb;
  if (d < S_rb) { w_r12[d] = conv_tw(r12, 64, 64, 16, d); return; }
  d -= S_rb;
  if (d < S_rb) { w_r21[d] = conv_tw(r21, 64, 64, 16, d); return; }
  d -= S_rb;
  if (d < S_rb) { w_r22[d] = conv_tw(r22, 64, 64, 16, d); return; }
  d -= S_rb;
  if (d < S_up) {
    int t = d & 3, oi = (d >> 2) & 3, ob = (d >> 4) & 15, ci = d >> 8;
    upwt[d] = up_w[((size_t)(ob * 4 + oi) * 128 + ci) * 4 + t];
  }
}

// ---------------------------------------------------------------------------
// Tiled 3x3 conv, pad=1. Block: 8 rows x 128 cols x 4 outch. 256 threads.
// Input: up to 3 concatenated 64-ch tensors. Double-buffered LDS staging of
// 4 input channels per chunk, 1 barrier/chunk, global prefetch 2 chunks ahead.
// wt layout: [c][ob][9][4]. mode: 1=relu, 2=sigmoid for o>=18, 3=residual
// ---------------------------------------------------------------------------
__global__ __launch_bounds__(256, 2) void conv3x3_t(
    const float* __restrict__ in0, const float* __restrict__ in1,
    const float* __restrict__ in2, const float* __restrict__ wt,
    const float* __restrict__ bias, const float* __restrict__ res,
    float* __restrict__ out, int Cin, int O, int Oq, int mode) {
  __shared__ float sb[2][5120];  // [buf][4c][10 rows][128 cols]
  const int tid = threadIdx.x;
  const int tx = tid & 31, ty = tid >> 5;
  const int y0 = blockIdx.x * 8;
  const int ob = blockIdx.y;
  const int n = blockIdx.z;

  float4 pf[5];
  auto loadc = [&](int cc) {
#pragma unroll
    for (int i = 0; i < 5; ++i) {
      int fi = tid + i * 256;
      int col4 = fi & 31;
      int rw = (fi >> 5) % 10;
      int cq = (fi >> 5) / 10;
      int c = cc + cq;
      const float* bp = (c < 64) ? in0 : ((c < 128) ? in1 : in2);
      const float* p = bp + ((size_t)n * 64 + (c & 63)) * HW;
      int gy = y0 - 1 + rw;
      if ((unsigned)gy < 128u)
        pf[i] = *(const float4*)(p + gy * 128 + col4 * 4);
      else
        pf[i] = make_float4(0.f, 0.f, 0.f, 0.f);
    }
  };
  auto storec = [&](int bsel) {
#pragma unroll
    for (int i = 0; i < 5; ++i) {
      int fi = tid + i * 256;
      *(float4*)&sb[bsel][fi * 4] = pf[i];
    }
  };

  float acc0[4] = {0.f, 0.f, 0.f, 0.f};
  float acc1[4] = {0.f, 0.f, 0.f, 0.f};
  float acc2[4] = {0.f, 0.f, 0.f, 0.f};
  float acc3[4] = {0.f, 0.f, 0.f, 0.f};

  const int nch = Cin >> 2;
  loadc(0);
  storec(0);
  loadc(4);
  __syncthreads();

  for (int ch = 0; ch < nch; ++ch) {
    int bsel = ch & 1;
    if (ch + 1 < nch) {
      storec(bsel ^ 1);
      if (ch + 2 < nch) loadc((ch + 2) * 4);
    }
    int cc = ch * 4;
#pragma unroll
    for (int cq = 0; cq < 4; ++cq) {
      const float* wp = wt + (((size_t)(cc + cq) * Oq + ob) * 36);
      float4 wv[9];
#pragma unroll
      for (int k = 0; k < 9; ++k) wv[k] = *(const float4*)(wp + k * 4);
      const float* srow = &sb[bsel][cq * 1280 + tx * 4];
#pragma unroll
      for (int ky = 0; ky < 3; ++ky) {
        float4 m = *(const float4*)(srow + (ty + ky) * 128);
        float v0 = __shfl_up(m.w, 1);
        if (tx == 0) v0 = 0.f;
        float v5 = __shfl_down(m.x, 1);
        if (tx == 31) v5 = 0.f;
        float vv[6] = {v0, m.x, m.y, m.z, m.w, v5};
        float4 wa = wv[ky * 3 + 0];
        float4 wb = wv[ky * 3 + 1];
        float4 wc = wv[ky * 3 + 2];
#pragma unroll
        for (int j = 0; j < 4; ++j) {
          acc0[j] = fmaf(wa.x, vv[j], acc0[j]);
          acc0[j] = fmaf(wb.x, vv[j + 1], acc0[j]);
          acc0[j] = fmaf(wc.x, vv[j + 2], acc0[j]);
          acc1[j] = fmaf(wa.y, vv[j], acc1[j]);
          acc1[j] = fmaf(wb.y, vv[j + 1], acc1[j]);
          acc1[j] = fmaf(wc.y, vv[j + 2], acc1[j]);
          acc2[j] = fmaf(wa.z, vv[j], acc2[j]);
          acc2[j] = fmaf(wb.z, vv[j + 1], acc2[j]);
          acc2[j] = fmaf(wc.z, vv[j + 2], acc2[j]);
          acc3[j] = fmaf(wa.w, vv[j], acc3[j]);
          acc3[j] = fmaf(wb.w, vv[j + 1], acc3[j]);
          acc3[j] = fmaf(wc.w, vv[j + 2], acc3[j]);
        }
      }
    }
    __syncthreads();
  }

  int y = y0 + ty;
  auto epi = [&](int oi, float (&a)[4]) {
    int o = ob * 4 + oi;
    if (o >= O) return;
    float bv = bias[o];
    float v[4];
#pragma unroll
    for (int j = 0; j < 4; ++j) v[j] = a[j] + bv;
    size_t base = ((size_t)(n * O + o)) * HW + (size_t)y * 128 + tx * 4;
    if (mode == 1) {
#pragma unroll
      for (int j = 0; j < 4; ++j) v[j] = fmaxf(v[j], 0.f);
    } else if (mode == 2) {
      if (o >= 18) {
#pragma unroll
        for (int j = 0; j < 4; ++j) v[j] = 1.f / (1.f + expf(-v[j]));
      }
    } else if (mode == 3) {
      float4 rv = *(const float4*)(res + base);
      v[0] += rv.x; v[1] += rv.y; v[2] += rv.z; v[3] += rv.w;
    }
    float4 val;
    val.x = v[0]; val.y = v[1]; val.z = v[2]; val.w = v[3];
    *(float4*)(out + base) = val;
  };
  epi(0, acc0);
  epi(1, acc1);
  epi(2, acc2);
  epi(3, acc3);
}

// ---------------------------------------------------------------------------
// Fused nearest-x2 upsample + 2x2 valid conv + zero pad (bottom/right).
// Exploits structure: out(y,x) = sum_t w[t] * xd(row_t, col_t) with rows
// {y>>1,(y+1)>>1}, cols {x>>1,(x+1)>>1}. Block: 8 rows x 128 cols x 4 o.
// uw layout: [ci][ob][oi][4 taps]
// ---------------------------------------------------------------------------
__global__ __launch_bounds__(256, 2) void upconv_t(
    const float* __restrict__ xd, const float* __restrict__ uw,
    const float* __restrict__ bias, float* __restrict__ out) {
  __shared__ float su[2][1280];  // [buf][4ci][5 rows][64 cols]
  const int tid = threadIdx.x;
  const int tx = tid & 31, ty = tid >> 5;
  const int y0 = blockIdx.x * 8;
  const int ob = blockIdx.y;
  const int n = blockIdx.z;

  float4 pf[2];
  auto loadu = [&](int cc) {
#pragma unroll
    for (int i = 0; i < 2; ++i) {
      int fi = tid + i * 256;
      if (fi < 320) {
        int col4 = fi & 15;
        int rw = (fi >> 4) % 5;
        int cq = (fi >> 4) / 5;
        int c = cc + cq;
        int gr = min(y0 / 2 + rw, 63);
        pf[i] = *(const float4*)(xd + ((size_t)(n * 128 + c) * 64 + gr) * 64 +
                                 col4 * 4);
      }
    }
  };
  auto storeu = [&](int bsel) {
#pragma unroll
    for (int i = 0; i < 2; ++i) {
      int fi = tid + i * 256;
      if (fi < 320) *(float4*)&su[bsel][fi * 4] = pf[i];
    }
  };

  float acc0[4] = {0.f, 0.f, 0.f, 0.f};
  float acc1[4] = {0.f, 0.f, 0.f, 0.f};
  float acc2[4] = {0.f, 0.f, 0.f, 0.f};
  float acc3[4] = {0.f, 0.f, 0.f, 0.f};

  const int ra = ty >> 1, rb = (ty + 1) >> 1;
  const int c0 = tx * 2, c2 = min(tx * 2 + 2, 63);

  loadu(0);
  storeu(0);
  loadu(4);
  __syncthreads();

  for (int ch = 0; ch < 32; ++ch) {
    int bsel = ch & 1;
    if (ch + 1 < 32) {
      storeu(bsel ^ 1);
      if (ch + 2 < 32) loadu((ch + 2) * 4);
    }
    int cc = ch * 4;
#pragma unroll
    for (int cq = 0; cq < 4; ++cq) {
      const float* up = uw + ((size_t)(cc + cq) * 16 + ob) * 16;
      float4 u0 = *(const float4*)(up);
      float4 u1 = *(const float4*)(up + 4);
      float4 u2 = *(const float4*)(up + 8);
      float4 u3 = *(const float4*)(up + 12);
      const float* sa = &su[bsel][(cq * 5 + ra) * 64];
      const float* sbr = &su[bsel][(cq * 5 + rb) * 64];
      float la0 = sa[c0], la1 = sa[c0 + 1], la2 = sa[c2];
      float lb0 = sbr[c0], lb1 = sbr[c0 + 1], lb2 = sbr[c2];
      float vA[4] = {la0, la0, la1, la1};  // U(y,   x)
      float vB[4] = {la0, la1, la1, la2};  // U(y,   x+1)
      float vC[4] = {lb0, lb0, lb1, lb1};  // U(y+1, x)
      float vD[4] = {lb0, lb1, lb1, lb2};  // U(y+1, x+1)
#pragma unroll
      for (int j = 0; j < 4; ++j) {
        acc0[j] = fmaf(u0.x, vA[j], acc0[j]);
        acc0[j] = fmaf(u0.y, vB[j], acc0[j]);
        acc0[j] = fmaf(u0.z, vC[j], acc0[j]);
        acc0[j] = fmaf(u0.w, vD[j], acc0[j]);
        acc1[j] = fmaf(u1.x, vA[j], acc1[j]);
        acc1[j] = fmaf(u1.y, vB[j], acc1[j]);
        acc1[j] = fmaf(u1.z, vC[j], acc1[j]);
        acc1[j] = fmaf(u1.w, vD[j], acc1[j]);
        acc2[j] = fmaf(u2.x, vA[j], acc2[j]);
        acc2[j] = fmaf(u2.y, vB[j], acc2[j]);
        acc2[j] = fmaf(u2.z, vC[j], acc2[j]);
        acc2[j] = fmaf(u2.w, vD[j], acc2[j]);
        acc3[j] = fmaf(u3.x, vA[j], acc3[j]);
        acc3[j] = fmaf(u3.y, vB[j], acc3[j]);
        acc3[j] = fmaf(u3.z, vC[j], acc3[j]);
        acc3[j] = fmaf(u3.w, vD[j], acc3[j]);
      }
    }
    __syncthreads();
  }

  int y = y0 + ty;
  auto epi = [&](int oi, float (&a)[4]) {
    int o = ob * 4 + oi;
    float bv = bias[o];
    float v[4];
#pragma unroll
    for (int j = 0; j < 4; ++j) v[j] = a[j] + bv;
    if (tx == 31) v[3] = 0.f;  // out col 127 = pad
    if (y == 127) { v[0] = 0.f; v[1] = 0.f; v[2] = 0.f; v[3] = 0.f; }
    float4 val;
    val.x = v[0]; val.y = v[1]; val.z = v[2]; val.w = v[3];
    *(float4*)(out + ((size_t)(n * 64 + o)) * HW + (size_t)y * 128 + tx * 4) = val;
  };
  epi(0, acc0);
  epi(1, acc1);
  epi(2, acc2);
  epi(3, acc3);
}

// ---------------------------------------------------------------------------
// Modulated deformable conv 3x3 (unchanged from R0)
// ---------------------------------------------------------------------------
__global__ __launch_bounds__(256) void deform_kernel(
    const float* __restrict__ x, const float* __restrict__ offm,
    const float* __restrict__ wt, const float* __restrict__ bias,
    float* __restrict__ out) {
  __shared__ float s_off[27][64];
  __shared__ float s_wy[9][64];
  __shared__ float s_wx[9][64];
  __shared__ int s_iy[9][64];
  __shared__ int s_ix[9][64];
  __shared__ float s_samp[16][9][64];

  int tid = threadIdx.x;
  int x0 = blockIdx.x * 64;
  int y = blockIdx.y;
  int n = blockIdx.z;

  for (int idx = tid; idx < 27 * 64; idx += 256) {
    int ch = idx >> 6, px = idx & 63;
    s_off[ch][px] = offm[((size_t)(n * 27 + ch) * 128 + y) * 128 + x0 + px];
  }
  __syncthreads();
  for (int idx = tid; idx < 9 * 64; idx += 256) {
    int k = idx >> 6, px = idx & 63;
    int ky = k / 3 - 1, kx = k % 3 - 1;
    float py = s_off[2 * k][px] + (float)(ky + y);
    float pxx = s_off[2 * k + 1][px] + (float)(kx + x0 + px);
    float fy = floorf(py), fx = floorf(pxx);
    s_wy[k][px] = py - fy;
    s_wx[k][px] = pxx - fx;
    s_iy[k][px] = (int)fy;
    s_ix[k][px] = (int)fx;
  }
  __syncthreads();

  int o = tid & 63;
  int pg = tid >> 6;
  float acc[16];
#pragma unroll
  for (int i = 0; i < 16; ++i) acc[i] = 0.f;

  for (int cc = 0; cc < 4; ++cc) {
    int px = o;
    int c0 = cc * 16 + pg * 4;
    const float* xb = x + (size_t)(n * 64 + c0) * HW;
    for (int k = 0; k < 9; ++k) {
      int iy0 = s_iy[k][px], ix0 = s_ix[k][px];
      float wy = s_wy[k][px], wx = s_wx[k][px];
      float m = s_off[18 + k][px];
      float a00 = (1.f - wy) * (1.f - wx) * m;
      float a01 = (1.f - wy) * wx * m;
      float a10 = wy * (1.f - wx) * m;
      float a11 = wy * wx * m;
      bool vy0 = (unsigned)iy0 < 128u, vy1 = (unsigned)(iy0 + 1) < 128u;
      bool vx0 = (unsigned)ix0 < 128u, vx1 = (unsigned)(ix0 + 1) < 128u;
      float f00 = (vy0 && vx0) ? a00 : 0.f;
      float f01 = (vy0 && vx1) ? a01 : 0.f;
      float f10 = (vy1 && vx0) ? a10 : 0.f;
      float f11 = (vy1 && vx1) ? a11 : 0.f;
      int y0c = min(max(iy0, 0), 127), y1c = min(max(iy0 + 1, 0), 127);
      int x0c = min(max(ix0, 0), 127), x1c = min(max(ix0 + 1, 0), 127);
      int i00 = y0c * 128 + x0c, i01 = y0c * 128 + x1c;
      int i10 = y1c * 128 + x0c, i11 = y1c * 128 + x1c;
#pragma unroll
      for (int j = 0; j < 4; ++j) {
        const float* xc = xb + (size_t)j * HW;
        float s = f00 * xc[i00] + f01 * xc[i01] + f10 * xc[i10] + f11 * xc[i11];
        s_samp[pg * 4 + j][k][px] = s;
      }
    }
    __syncthreads();
    for (int ci = 0; ci < 16; ++ci) {
      int c = cc * 16 + ci;
      const float* wrow = wt + (size_t)c * 9 * 64 + o;
#pragma unroll
      for (int k = 0; k < 9; ++k) {
        float wv = wrow[k * 64];
        const float4* s4 = (const float4*)(&s_samp[ci][k][pg * 16]);
        float4 a0 = s4[0], a1 = s4[1], a2 = s4[2], a3 = s4[3];
        acc[0] = fmaf(wv, a0.x, acc[0]);
        acc[1] = fmaf(wv, a0.y, acc[1]);
        acc[2] = fmaf(wv, a0.z, acc[2]);
        acc[3] = fmaf(wv, a0.w, acc[3]);
        acc[4] = fmaf(wv, a1.x, acc[4]);
        acc[5] = fmaf(wv, a1.y, acc[5]);
        acc[6] = fmaf(wv, a1.z, acc[6]);
        acc[7] = fmaf(wv, a1.w, acc[7]);
        acc[8] = fmaf(wv, a2.x, acc[8]);
        acc[9] = fmaf(wv, a2.y, acc[9]);
        acc[10] = fmaf(wv, a2.z, acc[10]);
        acc[11] = fmaf(wv, a2.w, acc[11]);
        acc[12] = fmaf(wv, a3.x, acc[12]);
        acc[13] = fmaf(wv, a3.y, acc[13]);
        acc[14] = fmaf(wv, a3.z, acc[14]);
        acc[15] = fmaf(wv, a3.w, acc[15]);
      }
    }
    __syncthreads();
  }

  float* s_ob = &s_samp[0][0][0];
  float bv = bias[o];
#pragma unroll
  for (int i = 0; i < 16; ++i) s_ob[o * 65 + pg * 16 + i] = acc[i] + bv;
  __syncthreads();
  for (int idx = tid; idx < 4096; idx += 256) {
    int oo = idx >> 6, pp = idx & 63;
    out[((size_t)(n * 64 + oo) * 128 + y) * 128 + x0 + pp] = s_ob[oo * 65 + pp];
  }
}

// ---------------------------------------------------------------------------
extern "C" void kernel_launch(void* const* d_in, const int* in_sizes, int n_in,
                              void* d_out, int out_size, void* d_ws, size_t ws_size,
                              hipStream_t stream) {
  const float* xd = (const float*)d_in[0];
  const float* xl = (const float*)d_in[1];
  const float* xr = (const float*)d_in[2];
  const float* up_w = (const float*)d_in[3];
  const float* up_b = (const float*)d_in[4];
  const float* offl_w = (const float*)d_in[5];
  const float* offl_b = (const float*)d_in[6];
  const float* dl_w = (const float*)d_in[7];
  const float* dl_b = (const float*)d_in[8];
  const float* offr_w = (const float*)d_in[9];
  const float* offr_b = (const float*)d_in[10];
  const float* dr_w = (const float*)d_in[11];
  const float* dr_b = (const float*)d_in[12];
  const float* cv_w = (const float*)d_in[13];
  const float* cv_b = (const float*)d_in[14];
  const float* rb1_w1 = (const float*)d_in[15];
  const float* rb1_w2 = (const float*)d_in[16];
  const float* rb2_w1 = (const float*)d_in[17];
  const float* rb2_w2 = (const float*)d_in[18];
  const float* rb1_b1 = (const float*)d_in[19];
  const float* rb1_b2 = (const float*)d_in[20];
  const float* rb2_b1 = (const float*)d_in[21];
  const float* rb2_b2 = (const float*)d_in[22];

  float* ws = (float*)d_ws;
  float* xdp = ws;                   // 2097152
  float* xl2 = ws + 2097152;         // 2097152
  float* xr2 = ws + 4194304;         // 2097152
  float* t0 = ws + 6291456;          // 2097152
  float* t1 = ws + 8388608;          // 2097152
  float* t2 = ws + 10485760;         // 2097152
  float* ol = ws + 12582912;         // 884736
  float* orr = ws + 13467648;        // 884736
  float* wtl = ws + 14352384;        // 36864
  float* wtr = ws + 14389248;        // 36864
  float* w_offl = ws + 14426112;     // 48384
  float* w_offr = ws + 14474496;     // 48384
  float* w_cv = ws + 14522880;       // 110592
  float* w_r11 = ws + 14633472;      // 36864
  float* w_r12 = ws + 14670336;      // 36864
  float* w_r21 = ws + 14707200;      // 36864
  float* w_r22 = ws + 14744064;      // 36864
  float* upwt = ws + 14780928;       // 32768
  float* outp = (float*)d_out;

  hipLaunchKernelGGL(prep_kernel, dim3(1802), dim3(256), 0, stream,
                     dl_w, dr_w, offl_w, offr_w, cv_w, rb1_w1, rb1_w2, rb2_w1,
                     rb2_w2, up_w, wtl, wtr, w_offl, w_offr, w_cv, w_r11,
                     w_r12, w_r21, w_r22, upwt);
  hipLaunchKernelGGL(upconv_t, dim3(16, 16, 2), dim3(256), 0, stream,
                     xd, upwt, up_b, xdp);
  hipLaunchKernelGGL(conv3x3_t, dim3(16, 7, 2), dim3(256), 0, stream,
                     xl, xr, xdp, w_offl, offl_b, (const float*)nullptr, ol,
                     192, 27, 7, 2);
  hipLaunchKernelGGL(deform_kernel, dim3(2, 128, 2), dim3(256), 0, stream,
                     xl, ol, wtl, dl_b, xl2);
  hipLaunchKernelGGL(conv3x3_t, dim3(16, 7, 2), dim3(256), 0, stream,
                     xl2, xr, xdp, w_offr, offr_b, (const float*)nullptr, orr,
                     192, 27, 7, 2);
  hipLaunchKernelGGL(deform_kernel, dim3(2, 128, 2), dim3(256), 0, stream,
                     xr, orr, wtr, dr_b, xr2);
  hipLaunchKernelGGL(conv3x3_t, dim3(16, 16, 2), dim3(256), 0, stream,
                     xl2, xr2, xdp, w_cv, cv_b, (const float*)nullptr, t0,
                     192, 64, 16, 1);
  hipLaunchKernelGGL(conv3x3_t, dim3(16, 16, 2), dim3(256), 0, stream,
                     t0, (const float*)nullptr, (const float*)nullptr,
                     w_r11, rb1_b1, (const float*)nullptr, t1, 64, 64, 16, 1);
  hipLaunchKernelGGL(conv3x3_t, dim3(16, 16, 2), dim3(256), 0, stream,
                     t1, (const float*)nullptr, (const float*)nullptr,
                     w_r12, rb1_b2, t0, t2, 64, 64, 16, 3);
  hipLaunchKernelGGL(conv3x3_t, dim3(16, 16, 2), dim3(256), 0, stream,
                     t2, (const float*)nullptr, (const float*)nullptr,
                     w_r21, rb2_b1, (const float*)nullptr, t1, 64, 64, 16, 1);
  hipLaunchKernelGGL(conv3x3_t, dim3(16, 16, 2), dim3(256), 0, stream,
                     t1, (const float*)nullptr, (const float*)nullptr,
                     w_r22, rb2_b2, t2, outp, 64, 64, 16, 3);
}

// Round 3
// 476.870 us; speedup vs baseline: 3.1576x; 3.1576x over previous
//
#include <hip/hip_runtime.h>
#include <math.h>

#define HW 16384

typedef unsigned short u16;
typedef __attribute__((ext_vector_type(8))) short short8;
typedef __attribute__((ext_vector_type(16))) float f32x16;

union U16B {
  uint4 u;
  short8 v;
  u16 s[8];
};

__device__ inline u16 f2b(float f) {
  unsigned u = __float_as_uint(f);
  u += 0x7FFF + ((u >> 16) & 1);
  return (u16)(u >> 16);
}
__device__ inline float b2f(u16 h) {
  return __uint_as_float(((unsigned)h) << 16);
}

// ---------------------------------------------------------------------------
// Prep: pack all weights.
//  - deform: w[o][c][k] -> wt[(c*9+k)][o]            (fp32)
//  - upconv: w[o][ci][t] -> uw[ci][ob][oi][t]        (fp32)
//  - mfma convs: per-lane A-fragments (bf16):
//    wpk[((((s*3+ky)*3+kx)*4+ks)*OT+ot)*512 + lane*8 + j] =
//      w[och=ot*32+(lane&31)][ch=s*64+ks*16+(lane>>5)*8+j][ky*3+kx]
// ---------------------------------------------------------------------------
__device__ inline u16 pack_frag(const float* __restrict__ w, int Cin, int O,
                                int OT, int d) {
  int j = d & 7;
  int lane = (d >> 3) & 63;
  int rest = d >> 9;
  int ot = rest % OT; rest /= OT;
  int ks = rest & 3; rest >>= 2;
  int kx = rest % 3; rest /= 3;
  int ky = rest % 3; int s = rest / 3;
  int och = ot * 32 + (lane & 31);
  int ch = s * 64 + ks * 16 + ((lane >> 5) << 3) + j;
  if (och >= O) return 0;
  return f2b(w[((size_t)och * Cin + ch) * 9 + ky * 3 + kx]);
}

__global__ __launch_bounds__(256) void prep_kernel(
    const float* __restrict__ dl_w, const float* __restrict__ dr_w,
    const float* __restrict__ up_w, const float* __restrict__ cv_w,
    const float* __restrict__ offl_w, const float* __restrict__ offr_w,
    const float* __restrict__ r1a, const float* __restrict__ r1b,
    const float* __restrict__ r2a, const float* __restrict__ r2b,
    float* __restrict__ wtl, float* __restrict__ wtr,
    float* __restrict__ upwt, u16* __restrict__ wcv,
    u16* __restrict__ wofl, u16* __restrict__ wofr,
    u16* __restrict__ wr1a, u16* __restrict__ wr1b,
    u16* __restrict__ wr2a, u16* __restrict__ wr2b) {
  int d = blockIdx.x * 256 + threadIdx.x;
  if (d < 36864) { int r = d >> 6, o = d & 63; wtl[d] = dl_w[o * 576 + r]; return; }
  d -= 36864;
  if (d < 36864) { int r = d >> 6, o = d & 63; wtr[d] = dr_w[o * 576 + r]; return; }
  d -= 36864;
  if (d < 32768) {
    int t = d & 3, oi = (d >> 2) & 3, ob = (d >> 4) & 15, ci = d >> 8;
    upwt[d] = up_w[((size_t)(ob * 4 + oi) * 128 + ci) * 4 + t];
    return;
  }
  d -= 32768;
  if (d < 110592) { wcv[d] = pack_frag(cv_w, 192, 64, 2, d); return; }
  d -= 110592;
  if (d < 55296) { wofl[d] = pack_frag(offl_w, 192, 27, 1, d); return; }
  d -= 55296;
  if (d < 55296) { wofr[d] = pack_frag(offr_w, 192, 27, 1, d); return; }
  d -= 55296;
  if (d < 36864) { wr1a[d] = pack_frag(r1a, 64, 64, 2, d); return; }
  d -= 36864;
  if (d < 36864) { wr1b[d] = pack_frag(r1b, 64, 64, 2, d); return; }
  d -= 36864;
  if (d < 36864) { wr2a[d] = pack_frag(r2a, 64, 64, 2, d); return; }
  d -= 36864;
  if (d < 36864) { wr2b[d] = pack_frag(r2b, 64, 64, 2, d); return; }
}

// ---------------------------------------------------------------------------
// NCHW fp32 -> NHWC bf16 converter (one 128-px row per block).
// blockIdx.y: 0..3 = (tensor: xl/xr) x (n)
// ---------------------------------------------------------------------------
__global__ __launch_bounds__(256) void cvt_nhwc(
    const float* __restrict__ xl, const float* __restrict__ xr,
    u16* __restrict__ xlh, u16* __restrict__ xrh) {
  __shared__ float sT[64 * 132];
  int tid = threadIdx.x;
  int y = blockIdx.x;
  int pid = blockIdx.y;
  const float* src = (pid >> 1) ? xr : xl;
  u16* dst = (pid >> 1) ? xrh : xlh;
  int n = pid & 1;
#pragma unroll
  for (int i = 0; i < 8; ++i) {
    int q = tid + i * 256;
    int ch = q >> 5, pxq = q & 31;
    float4 v = *(const float4*)(src + ((size_t)(n * 64 + ch)) * HW + y * 128 + pxq * 4);
    *(float4*)&sT[ch * 132 + pxq * 4] = v;
  }
  __syncthreads();
  int px = tid >> 1, half = tid & 1;
  u16* op = dst + (((size_t)(n * 128 + y)) * 128 + px) * 64 + half * 32;
#pragma unroll
  for (int c = 0; c < 4; ++c) {
    uint4 v;
    int ob = (half * 32 + c * 8);
    v.x = (unsigned)f2b(sT[(ob + 0) * 132 + px]) | ((unsigned)f2b(sT[(ob + 1) * 132 + px]) << 16);
    v.y = (unsigned)f2b(sT[(ob + 2) * 132 + px]) | ((unsigned)f2b(sT[(ob + 3) * 132 + px]) << 16);
    v.z = (unsigned)f2b(sT[(ob + 4) * 132 + px]) | ((unsigned)f2b(sT[(ob + 5) * 132 + px]) << 16);
    v.w = (unsigned)f2b(sT[(ob + 6) * 132 + px]) | ((unsigned)f2b(sT[(ob + 7) * 132 + px]) << 16);
    *(uint4*)(op + c * 8) = v;
  }
}

// ---------------------------------------------------------------------------
// MFMA 3x3 conv, pad=1, inputs NHWC bf16 (up to 3 concatenated 64-ch segs).
// Block = one image row (128 px), 4 waves; wave w owns px [w*32, w*32+32).
// D[och][px] = sum W[och][ch] * X[ch][px] via v_mfma_f32_32x32x16_bf16:
//   A=weights (row=och=lane&31, k=ch=(lane>>5)*8+j)  [prep-packed per-lane]
//   B=input   (col=px =lane&31, k=ch=(lane>>5)*8+j)  [ds_read_b128]
//   C: col=lane&31=px, row=(reg&3)+8*(reg>>2)+4*(lane>>5)=och  [m74/m101]
// LDS: [cg(8)][px_h(130)][8ch] 16B chunks, double-buffered, halo cols zeroed.
// mode: 1=relu, 2=sigmoid och>=18 (NCHW out), 3=+residual
// ---------------------------------------------------------------------------
__global__ __launch_bounds__(256) void mfconv(
    const u16* __restrict__ in0, const u16* __restrict__ in1,
    const u16* __restrict__ in2, const u16* __restrict__ wpk,
    const float* __restrict__ bias, const u16* __restrict__ resh,
    float* __restrict__ outF, u16* __restrict__ outH,
    int nseg, int OT, int O, int mode) {
  __shared__ __align__(16) u16 sx[2][8 * 130 * 8];
  const int tid = threadIdx.x;
  const int lane = tid & 63;
  const int w = tid >> 6;
  const int y = blockIdx.x;
  const int n = blockIdx.z;

  // zero halo columns in both buffers (px_h = 0 and 129)
  if (tid < 32) {
    int b = tid >> 4, e = (tid >> 3) & 1, cg = tid & 7;
    uint4 z = make_uint4(0, 0, 0, 0);
    *(uint4*)&sx[b][(cg * 130 + (e ? 129 : 0)) * 8] = z;
  }

  auto stage = [&](int buf, const u16* src, int row) {
#pragma unroll
    for (int i = 0; i < 4; ++i) {
      int q = tid + i * 256;
      int px = q >> 3, cg = q & 7;
      uint4 v = *(const uint4*)(src + (((size_t)(n * 128 + row)) * 128 + px) * 64 + cg * 8);
      *(uint4*)&sx[buf][(cg * 130 + px + 1) * 8] = v;
    }
  };

  f32x16 acc0, acc1;
#pragma unroll
  for (int i = 0; i < 16; ++i) { acc0[i] = 0.f; acc1[i] = 0.f; }

  const int kylo = (y == 0) ? 1 : 0;
  const int kyhi = (y == 127) ? 1 : 2;
  const int nky = kyhi - kylo + 1;
  const int ni = nseg * nky;
  const int pxb = (w << 5) + (lane & 31);
  const int hb = lane >> 5;

  stage(0, in0, y + kylo - 1);
  int cur = 0;
  for (int i = 0; i < ni; ++i) {
    int s = i / nky, ky = kylo + (i % nky);
    __syncthreads();
    if (i + 1 < ni) {
      int i2 = i + 1;
      int s2 = i2 / nky, ky2 = kylo + (i2 % nky);
      const u16* sp = (s2 == 0) ? in0 : ((s2 == 1) ? in1 : in2);
      stage(cur ^ 1, sp, y + ky2 - 1);
    }
    const u16* wb = wpk + (size_t)(s * 3 + ky) * 3 * 4 * OT * 512;
#pragma unroll
    for (int kx = 0; kx < 3; ++kx) {
#pragma unroll
      for (int ks = 0; ks < 4; ++ks) {
        U16B bf;
        bf.u = *(const uint4*)&sx[cur][((ks * 2 + hb) * 130 + pxb + kx) * 8];
        const u16* wp = wb + ((size_t)(kx * 4 + ks) * OT) * 512 + lane * 8;
        U16B a0;
        a0.u = *(const uint4*)wp;
        acc0 = __builtin_amdgcn_mfma_f32_32x32x16_bf16(a0.v, bf.v, acc0, 0, 0, 0);
        if (OT == 2) {
          U16B a1;
          a1.u = *(const uint4*)(wp + 512);
          acc1 = __builtin_amdgcn_mfma_f32_32x32x16_bf16(a1.v, bf.v, acc1, 0, 0, 0);
        }
      }
    }
    cur ^= 1;
  }

  // epilogue
  const size_t pixbase = ((size_t)(n * 128 + y)) * 128 + pxb;
  if (outH) {
#pragma unroll
    for (int ot = 0; ot < 2; ++ot) {
      if (ot >= OT) break;
      f32x16 A = (ot == 0) ? acc0 : acc1;
#pragma unroll
      for (int q = 0; q < 4; ++q) {
        int oo = ot * 32 + 8 * q + 4 * hb;
        float v[4];
#pragma unroll
        for (int r = 0; r < 4; ++r) v[r] = A[q * 4 + r] + bias[oo + r];
        if (mode == 1) {
#pragma unroll
          for (int r = 0; r < 4; ++r) v[r] = fmaxf(v[r], 0.f);
        } else if (mode == 3) {
          ushort4 rv = *(const ushort4*)(resh + pixbase * 64 + oo);
          v[0] += b2f(rv.x); v[1] += b2f(rv.y); v[2] += b2f(rv.z); v[3] += b2f(rv.w);
        }
        ushort4 h;
        h.x = f2b(v[0]); h.y = f2b(v[1]); h.z = f2b(v[2]); h.w = f2b(v[3]);
        *(ushort4*)(outH + pixbase * 64 + oo) = h;
      }
    }
  } else {
#pragma unroll
    for (int ot = 0; ot < 2; ++ot) {
      if (ot >= OT) break;
      f32x16 A = (ot == 0) ? acc0 : acc1;
#pragma unroll
      for (int q = 0; q < 4; ++q) {
        int oo = ot * 32 + 8 * q + 4 * hb;
#pragma unroll
        for (int r = 0; r < 4; ++r) {
          int och = oo + r;
          if (och >= O) continue;
          float v = A[q * 4 + r] + bias[och];
          if (mode == 2) {
            if (och >= 18) v = 1.f / (1.f + expf(-v));
          } else if (mode == 3) {
            v += b2f(resh[pixbase * 64 + och]);
          }
          outF[((size_t)(n * O + och)) * HW + y * 128 + pxb] = v;
        }
      }
    }
  }
}

// ---------------------------------------------------------------------------
// Fused nearest-x2 upsample + 2x2 valid conv + zero pad -> NHWC bf16.
// ---------------------------------------------------------------------------
__global__ __launch_bounds__(256) void upconv_t(
    const float* __restrict__ xd, const float* __restrict__ uw,
    const float* __restrict__ bias, u16* __restrict__ outH) {
  __shared__ float su[2][1280];
  const int tid = threadIdx.x;
  const int tx = tid & 31, ty = tid >> 5;
  const int y0 = blockIdx.x * 8;
  const int ob = blockIdx.y;
  const int n = blockIdx.z;

  float4 pf[2];
  auto loadu = [&](int cc) {
#pragma unroll
    for (int i = 0; i < 2; ++i) {
      int fi = tid + i * 256;
      if (fi < 320) {
        int col4 = fi & 15;
        int rw = (fi >> 4) % 5;
        int cq = (fi >> 4) / 5;
        int c = cc + cq;
        int gr = min(y0 / 2 + rw, 63);
        pf[i] = *(const float4*)(xd + ((size_t)(n * 128 + c) * 64 + gr) * 64 + col4 * 4);
      }
    }
  };
  auto storeu = [&](int bsel) {
#pragma unroll
    for (int i = 0; i < 2; ++i) {
      int fi = tid + i * 256;
      if (fi < 320) *(float4*)&su[bsel][fi * 4] = pf[i];
    }
  };

  float acc0[4] = {0.f, 0.f, 0.f, 0.f};
  float acc1[4] = {0.f, 0.f, 0.f, 0.f};
  float acc2[4] = {0.f, 0.f, 0.f, 0.f};
  float acc3[4] = {0.f, 0.f, 0.f, 0.f};

  const int ra = ty >> 1, rb = (ty + 1) >> 1;
  const int c0 = tx * 2, c2 = min(tx * 2 + 2, 63);

  loadu(0);
  storeu(0);
  loadu(4);
  __syncthreads();

  for (int ch = 0; ch < 32; ++ch) {
    int bsel = ch & 1;
    if (ch + 1 < 32) {
      storeu(bsel ^ 1);
      if (ch + 2 < 32) loadu((ch + 2) * 4);
    }
    int cc = ch * 4;
#pragma unroll
    for (int cq = 0; cq < 4; ++cq) {
      const float* up = uw + ((size_t)(cc + cq) * 16 + ob) * 16;
      float4 u0 = *(const float4*)(up);
      float4 u1 = *(const float4*)(up + 4);
      float4 u2 = *(const float4*)(up + 8);
      float4 u3 = *(const float4*)(up + 12);
      const float* sa = &su[bsel][(cq * 5 + ra) * 64];
      const float* sbr = &su[bsel][(cq * 5 + rb) * 64];
      float la0 = sa[c0], la1 = sa[c0 + 1], la2 = sa[c2];
      float lb0 = sbr[c0], lb1 = sbr[c0 + 1], lb2 = sbr[c2];
      float vA[4] = {la0, la0, la1, la1};
      float vB[4] = {la0, la1, la1, la2};
      float vC[4] = {lb0, lb0, lb1, lb1};
      float vD[4] = {lb0, lb1, lb1, lb2};
#pragma unroll
      for (int j = 0; j < 4; ++j) {
        acc0[j] = fmaf(u0.x, vA[j], acc0[j]);
        acc0[j] = fmaf(u0.y, vB[j], acc0[j]);
        acc0[j] = fmaf(u0.z, vC[j], acc0[j]);
        acc0[j] = fmaf(u0.w, vD[j], acc0[j]);
        acc1[j] = fmaf(u1.x, vA[j], acc1[j]);
        acc1[j] = fmaf(u1.y, vB[j], acc1[j]);
        acc1[j] = fmaf(u1.z, vC[j], acc1[j]);
        acc1[j] = fmaf(u1.w, vD[j], acc1[j]);
        acc2[j] = fmaf(u2.x, vA[j], acc2[j]);
        acc2[j] = fmaf(u2.y, vB[j], acc2[j]);
        acc2[j] = fmaf(u2.z, vC[j], acc2[j]);
        acc2[j] = fmaf(u2.w, vD[j], acc2[j]);
        acc3[j] = fmaf(u3.x, vA[j], acc3[j]);
        acc3[j] = fmaf(u3.y, vB[j], acc3[j]);
        acc3[j] = fmaf(u3.z, vC[j], acc3[j]);
        acc3[j] = fmaf(u3.w, vD[j], acc3[j]);
      }
    }
    __syncthreads();
  }

  int y = y0 + ty;
  float b0 = bias[ob * 4 + 0], b1 = bias[ob * 4 + 1];
  float b2 = bias[ob * 4 + 2], b3 = bias[ob * 4 + 3];
#pragma unroll
  for (int j = 0; j < 4; ++j) {
    int px = tx * 4 + j;
    float v0 = acc0[j] + b0, v1 = acc1[j] + b1, v2 = acc2[j] + b2, v3 = acc3[j] + b3;
    if (y == 127 || px == 127) { v0 = 0.f; v1 = 0.f; v2 = 0.f; v3 = 0.f; }
    ushort4 h;
    h.x = f2b(v0); h.y = f2b(v1); h.z = f2b(v2); h.w = f2b(v3);
    *(ushort4*)(outH + (((size_t)(n * 128 + y)) * 128 + px) * 64 + ob * 4) = h;
  }
}

// ---------------------------------------------------------------------------
// Modulated deformable conv 3x3; x fp32 NCHW, offm fp32 NCHW, out NHWC bf16.
// ---------------------------------------------------------------------------
__global__ __launch_bounds__(256) void deform_kernel(
    const float* __restrict__ x, const float* __restrict__ offm,
    const float* __restrict__ wt, const float* __restrict__ bias,
    u16* __restrict__ outH) {
  __shared__ float s_off[27][64];
  __shared__ float s_wy[9][64];
  __shared__ float s_wx[9][64];
  __shared__ int s_iy[9][64];
  __shared__ int s_ix[9][64];
  __shared__ float s_samp[16][9][64];

  int tid = threadIdx.x;
  int x0 = blockIdx.x * 64;
  int y = blockIdx.y;
  int n = blockIdx.z;

  for (int idx = tid; idx < 27 * 64; idx += 256) {
    int ch = idx >> 6, px = idx & 63;
    s_off[ch][px] = offm[((size_t)(n * 27 + ch) * 128 + y) * 128 + x0 + px];
  }
  __syncthreads();
  for (int idx = tid; idx < 9 * 64; idx += 256) {
    int k = idx >> 6, px = idx & 63;
    int ky = k / 3 - 1, kx = k % 3 - 1;
    float py = s_off[2 * k][px] + (float)(ky + y);
    float pxx = s_off[2 * k + 1][px] + (float)(kx + x0 + px);
    float fy = floorf(py), fx = floorf(pxx);
    s_wy[k][px] = py - fy;
    s_wx[k][px] = pxx - fx;
    s_iy[k][px] = (int)fy;
    s_ix[k][px] = (int)fx;
  }
  __syncthreads();

  int o = tid & 63;
  int pg = tid >> 6;
  float acc[16];
#pragma unroll
  for (int i = 0; i < 16; ++i) acc[i] = 0.f;

  for (int cc = 0; cc < 4; ++cc) {
    int px = o;
    int c0 = cc * 16 + pg * 4;
    const float* xb = x + (size_t)(n * 64 + c0) * HW;
    for (int k = 0; k < 9; ++k) {
      int iy0 = s_iy[k][px], ix0 = s_ix[k][px];
      float wy = s_wy[k][px], wx = s_wx[k][px];
      float m = s_off[18 + k][px];
      float a00 = (1.f - wy) * (1.f - wx) * m;
      float a01 = (1.f - wy) * wx * m;
      float a10 = wy * (1.f - wx) * m;
      float a11 = wy * wx * m;
      bool vy0 = (unsigned)iy0 < 128u, vy1 = (unsigned)(iy0 + 1) < 128u;
      bool vx0 = (unsigned)ix0 < 128u, vx1 = (unsigned)(ix0 + 1) < 128u;
      float f00 = (vy0 && vx0) ? a00 : 0.f;
      float f01 = (vy0 && vx1) ? a01 : 0.f;
      float f10 = (vy1 && vx0) ? a10 : 0.f;
      float f11 = (vy1 && vx1) ? a11 : 0.f;
      int y0c = min(max(iy0, 0), 127), y1c = min(max(iy0 + 1, 0), 127);
      int x0c = min(max(ix0, 0), 127), x1c = min(max(ix0 + 1, 0), 127);
      int i00 = y0c * 128 + x0c, i01 = y0c * 128 + x1c;
      int i10 = y1c * 128 + x0c, i11 = y1c * 128 + x1c;
#pragma unroll
      for (int j = 0; j < 4; ++j) {
        const float* xc = xb + (size_t)j * HW;
        float s = f00 * xc[i00] + f01 * xc[i01] + f10 * xc[i10] + f11 * xc[i11];
        s_samp[pg * 4 + j][k][px] = s;
      }
    }
    __syncthreads();
    for (int ci = 0; ci < 16; ++ci) {
      int c = cc * 16 + ci;
      const float* wrow = wt + (size_t)c * 9 * 64 + o;
#pragma unroll
      for (int k = 0; k < 9; ++k) {
        float wv = wrow[k * 64];
        const float4* s4 = (const float4*)(&s_samp[ci][k][pg * 16]);
        float4 a0 = s4[0], a1 = s4[1], a2 = s4[2], a3 = s4[3];
        acc[0] = fmaf(wv, a0.x, acc[0]);
        acc[1] = fmaf(wv, a0.y, acc[1]);
        acc[2] = fmaf(wv, a0.z, acc[2]);
        acc[3] = fmaf(wv, a0.w, acc[3]);
        acc[4] = fmaf(wv, a1.x, acc[4]);
        acc[5] = fmaf(wv, a1.y, acc[5]);
        acc[6] = fmaf(wv, a1.z, acc[6]);
        acc[7] = fmaf(wv, a1.w, acc[7]);
        acc[8] = fmaf(wv, a2.x, acc[8]);
        acc[9] = fmaf(wv, a2.y, acc[9]);
        acc[10] = fmaf(wv, a2.z, acc[10]);
        acc[11] = fmaf(wv, a2.w, acc[11]);
        acc[12] = fmaf(wv, a3.x, acc[12]);
        acc[13] = fmaf(wv, a3.y, acc[13]);
        acc[14] = fmaf(wv, a3.z, acc[14]);
        acc[15] = fmaf(wv, a3.w, acc[15]);
      }
    }
    __syncthreads();
  }

  float* s_ob = &s_samp[0][0][0];
  float bv = bias[o];
#pragma unroll
  for (int i = 0; i < 16; ++i) s_ob[o * 65 + pg * 16 + i] = acc[i] + bv;
  __syncthreads();
  for (int idx = tid; idx < 2048; idx += 256) {
    int op2 = idx & 31, pp = idx >> 5;
    unsigned lo = f2b(s_ob[(op2 * 2) * 65 + pp]);
    unsigned hi = f2b(s_ob[(op2 * 2 + 1) * 65 + pp]);
    ((unsigned*)outH)[(((size_t)(n * 128 + y)) * 128 + x0 + pp) * 32 + op2] =
        lo | (hi << 16);
  }
}

// ---------------------------------------------------------------------------
extern "C" void kernel_launch(void* const* d_in, const int* in_sizes, int n_in,
                              void* d_out, int out_size, void* d_ws, size_t ws_size,
                              hipStream_t stream) {
  const float* xd = (const float*)d_in[0];
  const float* xl = (const float*)d_in[1];
  const float* xr = (const float*)d_in[2];
  const float* up_w = (const float*)d_in[3];
  const float* up_b = (const float*)d_in[4];
  const float* offl_w = (const float*)d_in[5];
  const float* offl_b = (const float*)d_in[6];
  const float* dl_w = (const float*)d_in[7];
  const float* dl_b = (const float*)d_in[8];
  const float* offr_w = (const float*)d_in[9];
  const float* offr_b = (const float*)d_in[10];
  const float* dr_w = (const float*)d_in[11];
  const float* dr_b = (const float*)d_in[12];
  const float* cv_w = (const float*)d_in[13];
  const float* cv_b = (const float*)d_in[14];
  const float* rb1_w1 = (const float*)d_in[15];
  const float* rb1_w2 = (const float*)d_in[16];
  const float* rb2_w1 = (const float*)d_in[17];
  const float* rb2_w2 = (const float*)d_in[18];
  const float* rb1_b1 = (const float*)d_in[19];
  const float* rb1_b2 = (const float*)d_in[20];
  const float* rb2_b1 = (const float*)d_in[21];
  const float* rb2_b2 = (const float*)d_in[22];

  float* ws = (float*)d_ws;
  float* ol = ws;                 // 884736
  float* orr = ws + 884736;       // 884736
  float* wtl = ws + 1769472;      // 36864
  float* wtr = ws + 1806336;      // 36864
  float* upwt = ws + 1843200;     // 32768
  u16* hb = (u16*)(ws + 1875968);
  u16* xlh = hb;                  // 2097152
  u16* xrh = hb + 2097152;
  u16* xdph = hb + 4194304;
  u16* xl2h = hb + 6291456;
  u16* xr2h = hb + 8388608;
  u16* t0h = hb + 10485760;
  u16* t1h = hb + 12582912;
  u16* t2h = hb + 14680064;
  u16* t3h = hb + 16777216;
  u16* wcv = hb + 18874368;       // 110592
  u16* wofl = hb + 18984960;      // 55296
  u16* wofr = hb + 19040256;      // 55296
  u16* wr1a = hb + 19095552;      // 36864
  u16* wr1b = hb + 19132416;
  u16* wr2a = hb + 19169280;
  u16* wr2b = hb + 19206144;
  float* outp = (float*)d_out;

  hipLaunchKernelGGL(prep_kernel, dim3(1856), dim3(256), 0, stream,
                     dl_w, dr_w, up_w, cv_w, offl_w, offr_w, rb1_w1, rb1_w2,
                     rb2_w1, rb2_w2, wtl, wtr, upwt, wcv, wofl, wofr, wr1a,
                     wr1b, wr2a, wr2b);
  hipLaunchKernelGGL(cvt_nhwc, dim3(128, 4), dim3(256), 0, stream,
                     xl, xr, xlh, xrh);
  hipLaunchKernelGGL(upconv_t, dim3(16, 16, 2), dim3(256), 0, stream,
                     xd, upwt, up_b, xdph);
  hipLaunchKernelGGL(mfconv, dim3(128, 1, 2), dim3(256), 0, stream,
                     xlh, xrh, xdph, wofl, offl_b, (const u16*)nullptr, ol,
                     (u16*)nullptr, 3, 1, 27, 2);
  hipLaunchKernelGGL(deform_kernel, dim3(2, 128, 2), dim3(256), 0, stream,
                     xl, ol, wtl, dl_b, xl2h);
  hipLaunchKernelGGL(mfconv, dim3(128, 1, 2), dim3(256), 0, stream,
                     xl2h, xrh, xdph, wofr, offr_b, (const u16*)nullptr, orr,
                     (u16*)nullptr, 3, 1, 27, 2);
  hipLaunchKernelGGL(deform_kernel, dim3(2, 128, 2), dim3(256), 0, stream,
                     xr, orr, wtr, dr_b, xr2h);
  hipLaunchKernelGGL(mfconv, dim3(128, 1, 2), dim3(256), 0, stream,
                     xl2h, xr2h, xdph, wcv, cv_b, (const u16*)nullptr,
                     (float*)nullptr, t0h, 3, 2, 64, 1);
  hipLaunchKernelGGL(mfconv, dim3(128, 1, 2), dim3(256), 0, stream,
                     t0h, (const u16*)nullptr, (const u16*)nullptr, wr1a,
                     rb1_b1, (const u16*)nullptr, (float*)nullptr, t1h,
                     1, 2, 64, 1);
  hipLaunchKernelGGL(mfconv, dim3(128, 1, 2), dim3(256), 0, stream,
                     t1h, (const u16*)nullptr, (const u16*)nullptr, wr1b,
                     rb1_b2, t0h, (float*)nullptr, t2h, 1, 2, 64, 3);
  hipLaunchKernelGGL(mfconv, dim3(128, 1, 2), dim3(256), 0, stream,
                     t2h, (const u16*)nullptr, (const u16*)nullptr, wr2a,
                     rb2_b1, (const u16*)nullptr, (float*)nullptr, t3h,
                     1, 2, 64, 1);
  hipLaunchKernelGGL(mfconv, dim3(128, 1, 2), dim3(256), 0, stream,
                     t3h, (const u16*)nullptr, (const u16*)nullptr, wr2b,
                     rb2_b2, t2h, outp, (u16*)nullptr, 1, 2, 64, 3);
}

// Round 4
// 369.019 us; speedup vs baseline: 4.0805x; 1.2923x over previous
//
#include <hip/hip_runtime.h>
#include <math.h>

#define HW 16384

typedef unsigned short u16;
typedef __attribute__((ext_vector_type(8))) short short8;
typedef __attribute__((ext_vector_type(16))) float f32x16;

union U16B {
  uint4 u;
  short8 v;
  u16 s[8];
};

__device__ inline u16 f2b(float f) {
  unsigned u = __float_as_uint(f);
  u += 0x7FFF + ((u >> 16) & 1);
  return (u16)(u >> 16);
}
__device__ inline float b2f(u16 h) {
  return __uint_as_float(((unsigned)h) << 16);
}

// ---------------------------------------------------------------------------
// Prep: pack all weights.
//  - upconv: w[o][ci][t] -> uw[ci][ob][oi][t]  (fp32)
//  - mfma 3x3 convs: per-lane A-fragments (bf16):
//    wpk[((((s*3+ky)*3+kx)*4+ks)*OT+ot)*512 + lane*8 + j] =
//      w[och=ot*32+(lane&31)][ch=s*64+ks*16+(lane>>5)*8+j][ky*3+kx]
//  - deform convs: wdk[((k*4+ks)*2+ot)*512 + lane*8 + j] =
//      w[och=ot*32+(lane&31)][c=ks*16+(lane>>5)*8+j][k]
// ---------------------------------------------------------------------------
__device__ inline u16 pack_frag(const float* __restrict__ w, int Cin, int O,
                                int OT, int d) {
  int j = d & 7;
  int lane = (d >> 3) & 63;
  int rest = d >> 9;
  int ot = rest % OT; rest /= OT;
  int ks = rest & 3; rest >>= 2;
  int kx = rest % 3; rest /= 3;
  int ky = rest % 3; int s = rest / 3;
  int och = ot * 32 + (lane & 31);
  int ch = s * 64 + ks * 16 + ((lane >> 5) << 3) + j;
  if (och >= O) return 0;
  return f2b(w[((size_t)och * Cin + ch) * 9 + ky * 3 + kx]);
}

__device__ inline u16 pack_def(const float* __restrict__ w, int d) {
  int j = d & 7;
  int lane = (d >> 3) & 63;
  int g = d >> 9;
  int ot = g & 1;
  int t = g >> 1;
  int ks = t & 3;
  int k = t >> 2;
  int och = ot * 32 + (lane & 31);
  int c = ks * 16 + ((lane >> 5) << 3) + j;
  return f2b(w[((size_t)och * 64 + c) * 9 + k]);
}

__global__ __launch_bounds__(256) void prep_kernel(
    const float* __restrict__ dl_w, const float* __restrict__ dr_w,
    const float* __restrict__ up_w, const float* __restrict__ cv_w,
    const float* __restrict__ offl_w, const float* __restrict__ offr_w,
    const float* __restrict__ r1a, const float* __restrict__ r1b,
    const float* __restrict__ r2a, const float* __restrict__ r2b,
    float* __restrict__ upwt, u16* __restrict__ wdl, u16* __restrict__ wdr,
    u16* __restrict__ wcv, u16* __restrict__ wofl, u16* __restrict__ wofr,
    u16* __restrict__ wr1a, u16* __restrict__ wr1b,
    u16* __restrict__ wr2a, u16* __restrict__ wr2b) {
  int d = blockIdx.x * 256 + threadIdx.x;
  if (d < 32768) {
    int t = d & 3, oi = (d >> 2) & 3, ob = (d >> 4) & 15, ci = d >> 8;
    upwt[d] = up_w[((size_t)(ob * 4 + oi) * 128 + ci) * 4 + t];
    return;
  }
  d -= 32768;
  if (d < 36864) { wdl[d] = pack_def(dl_w, d); return; }
  d -= 36864;
  if (d < 36864) { wdr[d] = pack_def(dr_w, d); return; }
  d -= 36864;
  if (d < 110592) { wcv[d] = pack_frag(cv_w, 192, 64, 2, d); return; }
  d -= 110592;
  if (d < 55296) { wofl[d] = pack_frag(offl_w, 192, 27, 1, d); return; }
  d -= 55296;
  if (d < 55296) { wofr[d] = pack_frag(offr_w, 192, 27, 1, d); return; }
  d -= 55296;
  if (d < 36864) { wr1a[d] = pack_frag(r1a, 64, 64, 2, d); return; }
  d -= 36864;
  if (d < 36864) { wr1b[d] = pack_frag(r1b, 64, 64, 2, d); return; }
  d -= 36864;
  if (d < 36864) { wr2a[d] = pack_frag(r2a, 64, 64, 2, d); return; }
  d -= 36864;
  if (d < 36864) { wr2b[d] = pack_frag(r2b, 64, 64, 2, d); return; }
}

// ---------------------------------------------------------------------------
// NCHW fp32 -> NHWC bf16 converter (one 128-px row per block).
// ---------------------------------------------------------------------------
__global__ __launch_bounds__(256) void cvt_nhwc(
    const float* __restrict__ xl, const float* __restrict__ xr,
    u16* __restrict__ xlh, u16* __restrict__ xrh) {
  __shared__ float sT[64 * 132];
  int tid = threadIdx.x;
  int y = blockIdx.x;
  int pid = blockIdx.y;
  const float* src = (pid >> 1) ? xr : xl;
  u16* dst = (pid >> 1) ? xrh : xlh;
  int n = pid & 1;
#pragma unroll
  for (int i = 0; i < 8; ++i) {
    int q = tid + i * 256;
    int ch = q >> 5, pxq = q & 31;
    float4 v = *(const float4*)(src + ((size_t)(n * 64 + ch)) * HW + y * 128 + pxq * 4);
    *(float4*)&sT[ch * 132 + pxq * 4] = v;
  }
  __syncthreads();
  int px = tid >> 1, half = tid & 1;
  u16* op = dst + (((size_t)(n * 128 + y)) * 128 + px) * 64 + half * 32;
#pragma unroll
  for (int c = 0; c < 4; ++c) {
    uint4 v;
    int ob = (half * 32 + c * 8);
    v.x = (unsigned)f2b(sT[(ob + 0) * 132 + px]) | ((unsigned)f2b(sT[(ob + 1) * 132 + px]) << 16);
    v.y = (unsigned)f2b(sT[(ob + 2) * 132 + px]) | ((unsigned)f2b(sT[(ob + 3) * 132 + px]) << 16);
    v.z = (unsigned)f2b(sT[(ob + 4) * 132 + px]) | ((unsigned)f2b(sT[(ob + 5) * 132 + px]) << 16);
    v.w = (unsigned)f2b(sT[(ob + 6) * 132 + px]) | ((unsigned)f2b(sT[(ob + 7) * 132 + px]) << 16);
    *(uint4*)(op + c * 8) = v;
  }
}

// ---------------------------------------------------------------------------
// MFMA 3x3 conv, pad=1, inputs NHWC bf16 (up to 3 concatenated 64-ch segs).
// (unchanged from R3 — passed)
// ---------------------------------------------------------------------------
__global__ __launch_bounds__(256) void mfconv(
    const u16* __restrict__ in0, const u16* __restrict__ in1,
    const u16* __restrict__ in2, const u16* __restrict__ wpk,
    const float* __restrict__ bias, const u16* __restrict__ resh,
    float* __restrict__ outF, u16* __restrict__ outH,
    int nseg, int OT, int O, int mode) {
  __shared__ __align__(16) u16 sx[2][8 * 130 * 8];
  const int tid = threadIdx.x;
  const int lane = tid & 63;
  const int w = tid >> 6;
  const int y = blockIdx.x;
  const int n = blockIdx.z;

  if (tid < 32) {
    int b = tid >> 4, e = (tid >> 3) & 1, cg = tid & 7;
    uint4 z = make_uint4(0, 0, 0, 0);
    *(uint4*)&sx[b][(cg * 130 + (e ? 129 : 0)) * 8] = z;
  }

  auto stage = [&](int buf, const u16* src, int row) {
#pragma unroll
    for (int i = 0; i < 4; ++i) {
      int q = tid + i * 256;
      int px = q >> 3, cg = q & 7;
      uint4 v = *(const uint4*)(src + (((size_t)(n * 128 + row)) * 128 + px) * 64 + cg * 8);
      *(uint4*)&sx[buf][(cg * 130 + px + 1) * 8] = v;
    }
  };

  f32x16 acc0, acc1;
#pragma unroll
  for (int i = 0; i < 16; ++i) { acc0[i] = 0.f; acc1[i] = 0.f; }

  const int kylo = (y == 0) ? 1 : 0;
  const int kyhi = (y == 127) ? 1 : 2;
  const int nky = kyhi - kylo + 1;
  const int ni = nseg * nky;
  const int pxb = (w << 5) + (lane & 31);
  const int hb = lane >> 5;

  stage(0, in0, y + kylo - 1);
  int cur = 0;
  for (int i = 0; i < ni; ++i) {
    int s = i / nky, ky = kylo + (i % nky);
    __syncthreads();
    if (i + 1 < ni) {
      int i2 = i + 1;
      int s2 = i2 / nky, ky2 = kylo + (i2 % nky);
      const u16* sp = (s2 == 0) ? in0 : ((s2 == 1) ? in1 : in2);
      stage(cur ^ 1, sp, y + ky2 - 1);
    }
    const u16* wb = wpk + (size_t)(s * 3 + ky) * 3 * 4 * OT * 512;
#pragma unroll
    for (int kx = 0; kx < 3; ++kx) {
#pragma unroll
      for (int ks = 0; ks < 4; ++ks) {
        U16B bf;
        bf.u = *(const uint4*)&sx[cur][((ks * 2 + hb) * 130 + pxb + kx) * 8];
        const u16* wp = wb + ((size_t)(kx * 4 + ks) * OT) * 512 + lane * 8;
        U16B a0;
        a0.u = *(const uint4*)wp;
        acc0 = __builtin_amdgcn_mfma_f32_32x32x16_bf16(a0.v, bf.v, acc0, 0, 0, 0);
        if (OT == 2) {
          U16B a1;
          a1.u = *(const uint4*)(wp + 512);
          acc1 = __builtin_amdgcn_mfma_f32_32x32x16_bf16(a1.v, bf.v, acc1, 0, 0, 0);
        }
      }
    }
    cur ^= 1;
  }

  const size_t pixbase = ((size_t)(n * 128 + y)) * 128 + pxb;
  if (outH) {
#pragma unroll
    for (int ot = 0; ot < 2; ++ot) {
      if (ot >= OT) break;
      f32x16 A = (ot == 0) ? acc0 : acc1;
#pragma unroll
      for (int q = 0; q < 4; ++q) {
        int oo = ot * 32 + 8 * q + 4 * hb;
        float v[4];
#pragma unroll
        for (int r = 0; r < 4; ++r) v[r] = A[q * 4 + r] + bias[oo + r];
        if (mode == 1) {
#pragma unroll
          for (int r = 0; r < 4; ++r) v[r] = fmaxf(v[r], 0.f);
        } else if (mode == 3) {
          ushort4 rv = *(const ushort4*)(resh + pixbase * 64 + oo);
          v[0] += b2f(rv.x); v[1] += b2f(rv.y); v[2] += b2f(rv.z); v[3] += b2f(rv.w);
        }
        ushort4 h;
        h.x = f2b(v[0]); h.y = f2b(v[1]); h.z = f2b(v[2]); h.w = f2b(v[3]);
        *(ushort4*)(outH + pixbase * 64 + oo) = h;
      }
    }
  } else {
#pragma unroll
    for (int ot = 0; ot < 2; ++ot) {
      if (ot >= OT) break;
      f32x16 A = (ot == 0) ? acc0 : acc1;
#pragma unroll
      for (int q = 0; q < 4; ++q) {
        int oo = ot * 32 + 8 * q + 4 * hb;
#pragma unroll
        for (int r = 0; r < 4; ++r) {
          int och = oo + r;
          if (och >= O) continue;
          float v = A[q * 4 + r] + bias[och];
          if (mode == 2) {
            if (och >= 18) v = 1.f / (1.f + expf(-v));
          } else if (mode == 3) {
            v += b2f(resh[pixbase * 64 + och]);
          }
          outF[((size_t)(n * O + och)) * HW + y * 128 + pxb] = v;
        }
      }
    }
  }
}

// ---------------------------------------------------------------------------
// Modulated deformable conv 3x3 via gather + MFMA.
// x NHWC bf16; offm NCHW fp32 (27 ch: dy,dx pairs + 9 masks pre-sigmoided);
// out NHWC bf16. Block = one row (128 px), 512 threads = 8 waves.
// Wave w: px-tile p2=w>>1 (32 px), k-half kh=w&1 (taps 0-4 / 5-8).
// Per (k,ks): each lane gathers 4 corner dwordx4 (8 ch) from NHWC, blends in
// fp32 with mask-folded validity coeffs, packs B-frag in registers, MFMA.
// Partial accs of the two k-halves combined through LDS.
// ---------------------------------------------------------------------------
__global__ __launch_bounds__(512) void deform_mf(
    const u16* __restrict__ xh, const float* __restrict__ offm,
    const u16* __restrict__ wpk, const float* __restrict__ bias,
    u16* __restrict__ outH) {
  __shared__ float s_off[27][128];
  __shared__ float s_red[4][2][16][64];
  const int tid = threadIdx.x;
  const int lane = tid & 63;
  const int w = tid >> 6;
  const int p2 = w >> 1;
  const int kh = w & 1;
  const int y = blockIdx.x;
  const int n = blockIdx.y;
  const int px = (p2 << 5) + (lane & 31);
  const int h = lane >> 5;

  for (int idx = tid; idx < 27 * 128; idx += 512) {
    int ch = idx >> 7, pp = idx & 127;
    s_off[ch][pp] = offm[((size_t)(n * 27 + ch) * 128 + y) * 128 + pp];
  }
  __syncthreads();

  f32x16 acc0, acc1;
#pragma unroll
  for (int i = 0; i < 16; ++i) { acc0[i] = 0.f; acc1[i] = 0.f; }

  const u16* xb = xh + ((size_t)n * HW) * 64;

#pragma unroll
  for (int kk = 0; kk < 5; ++kk) {
    if (kh && kk == 4) break;  // wave-uniform: k-half 1 has 4 taps
    const int k = kh * 5 + kk;
    const int ky = k / 3 - 1, kx = k % 3 - 1;
    float dy = s_off[2 * k][px];
    float dx = s_off[2 * k + 1][px];
    float m = s_off[18 + k][px];
    float py = dy + (float)(y + ky);
    float pxf = dx + (float)(px + kx);
    float fy = floorf(py), fxx = floorf(pxf);
    float wy = py - fy, wx = pxf - fxx;
    int iy0 = (int)fy, ix0 = (int)fxx;
    bool vy0 = (unsigned)iy0 < 128u, vy1 = (unsigned)(iy0 + 1) < 128u;
    bool vx0 = (unsigned)ix0 < 128u, vx1 = (unsigned)(ix0 + 1) < 128u;
    float omwy = 1.f - wy, omwx = 1.f - wx;
    float f00 = (vy0 && vx0) ? omwy * omwx * m : 0.f;
    float f01 = (vy0 && vx1) ? omwy * wx * m : 0.f;
    float f10 = (vy1 && vx0) ? wy * omwx * m : 0.f;
    float f11 = (vy1 && vx1) ? wy * wx * m : 0.f;
    int y0c = min(max(iy0, 0), 127), y1c = min(max(iy0 + 1, 0), 127);
    int x0c = min(max(ix0, 0), 127), x1c = min(max(ix0 + 1, 0), 127);
    const u16* r00 = xb + ((size_t)(y0c * 128 + x0c)) * 64;
    const u16* r01 = xb + ((size_t)(y0c * 128 + x1c)) * 64;
    const u16* r10 = xb + ((size_t)(y1c * 128 + x0c)) * 64;
    const u16* r11 = xb + ((size_t)(y1c * 128 + x1c)) * 64;
#pragma unroll
    for (int ks = 0; ks < 4; ++ks) {
      const int co = ks * 16 + h * 8;
      U16B u00, u01, u10, u11;
      u00.u = *(const uint4*)(r00 + co);
      u01.u = *(const uint4*)(r01 + co);
      u10.u = *(const uint4*)(r10 + co);
      u11.u = *(const uint4*)(r11 + co);
      unsigned dw[4];
#pragma unroll
      for (int jj = 0; jj < 4; ++jj) {
        float s0 = f00 * b2f(u00.s[2 * jj]) + f01 * b2f(u01.s[2 * jj]) +
                   f10 * b2f(u10.s[2 * jj]) + f11 * b2f(u11.s[2 * jj]);
        float s1 = f00 * b2f(u00.s[2 * jj + 1]) + f01 * b2f(u01.s[2 * jj + 1]) +
                   f10 * b2f(u10.s[2 * jj + 1]) + f11 * b2f(u11.s[2 * jj + 1]);
        dw[jj] = (unsigned)f2b(s0) | ((unsigned)f2b(s1) << 16);
      }
      U16B bf;
      bf.u = make_uint4(dw[0], dw[1], dw[2], dw[3]);
      const u16* wp = wpk + ((size_t)((k * 4 + ks) * 2)) * 512 + lane * 8;
      U16B a0, a1;
      a0.u = *(const uint4*)wp;
      a1.u = *(const uint4*)(wp + 512);
      acc0 = __builtin_amdgcn_mfma_f32_32x32x16_bf16(a0.v, bf.v, acc0, 0, 0, 0);
      acc1 = __builtin_amdgcn_mfma_f32_32x32x16_bf16(a1.v, bf.v, acc1, 0, 0, 0);
    }
  }

  if (kh == 1) {
#pragma unroll
    for (int i = 0; i < 16; ++i) {
      s_red[p2][0][i][lane] = acc0[i];
      s_red[p2][1][i][lane] = acc1[i];
    }
  }
  __syncthreads();
  if (kh == 0) {
    const size_t pixb = (((size_t)(n * 128 + y)) * 128 + px) * 64;
#pragma unroll
    for (int ot = 0; ot < 2; ++ot) {
      f32x16 A = ot ? acc1 : acc0;
#pragma unroll
      for (int q = 0; q < 4; ++q) {
        int oo = ot * 32 + 8 * q + 4 * h;
        float v[4];
#pragma unroll
        for (int r = 0; r < 4; ++r)
          v[r] = A[q * 4 + r] + s_red[p2][ot][q * 4 + r][lane] + bias[oo + r];
        ushort4 hh;
        hh.x = f2b(v[0]); hh.y = f2b(v[1]); hh.z = f2b(v[2]); hh.w = f2b(v[3]);
        *(ushort4*)(outH + pixb + oo) = hh;
      }
    }
  }
}

// ---------------------------------------------------------------------------
// Fused nearest-x2 upsample + 2x2 valid conv + zero pad -> NHWC bf16.
// (unchanged from R3)
// ---------------------------------------------------------------------------
__global__ __launch_bounds__(256) void upconv_t(
    const float* __restrict__ xd, const float* __restrict__ uw,
    const float* __restrict__ bias, u16* __restrict__ outH) {
  __shared__ float su[2][1280];
  const int tid = threadIdx.x;
  const int tx = tid & 31, ty = tid >> 5;
  const int y0 = blockIdx.x * 8;
  const int ob = blockIdx.y;
  const int n = blockIdx.z;

  float4 pf[2];
  auto loadu = [&](int cc) {
#pragma unroll
    for (int i = 0; i < 2; ++i) {
      int fi = tid + i * 256;
      if (fi < 320) {
        int col4 = fi & 15;
        int rw = (fi >> 4) % 5;
        int cq = (fi >> 4) / 5;
        int c = cc + cq;
        int gr = min(y0 / 2 + rw, 63);
        pf[i] = *(const float4*)(xd + ((size_t)(n * 128 + c) * 64 + gr) * 64 + col4 * 4);
      }
    }
  };
  auto storeu = [&](int bsel) {
#pragma unroll
    for (int i = 0; i < 2; ++i) {
      int fi = tid + i * 256;
      if (fi < 320) *(float4*)&su[bsel][fi * 4] = pf[i];
    }
  };

  float acc0[4] = {0.f, 0.f, 0.f, 0.f};
  float acc1[4] = {0.f, 0.f, 0.f, 0.f};
  float acc2[4] = {0.f, 0.f, 0.f, 0.f};
  float acc3[4] = {0.f, 0.f, 0.f, 0.f};

  const int ra = ty >> 1, rb = (ty + 1) >> 1;
  const int c0 = tx * 2, c2 = min(tx * 2 + 2, 63);

  loadu(0);
  storeu(0);
  loadu(4);
  __syncthreads();

  for (int ch = 0; ch < 32; ++ch) {
    int bsel = ch & 1;
    if (ch + 1 < 32) {
      storeu(bsel ^ 1);
      if (ch + 2 < 32) loadu((ch + 2) * 4);
    }
    int cc = ch * 4;
#pragma unroll
    for (int cq = 0; cq < 4; ++cq) {
      const float* up = uw + ((size_t)(cc + cq) * 16 + ob) * 16;
      float4 u0 = *(const float4*)(up);
      float4 u1 = *(const float4*)(up + 4);
      float4 u2 = *(const float4*)(up + 8);
      float4 u3 = *(const float4*)(up + 12);
      const float* sa = &su[bsel][(cq * 5 + ra) * 64];
      const float* sbr = &su[bsel][(cq * 5 + rb) * 64];
      float la0 = sa[c0], la1 = sa[c0 + 1], la2 = sa[c2];
      float lb0 = sbr[c0], lb1 = sbr[c0 + 1], lb2 = sbr[c2];
      float vA[4] = {la0, la0, la1, la1};
      float vB[4] = {la0, la1, la1, la2};
      float vC[4] = {lb0, lb0, lb1, lb1};
      float vD[4] = {lb0, lb1, lb1, lb2};
#pragma unroll
      for (int j = 0; j < 4; ++j) {
        acc0[j] = fmaf(u0.x, vA[j], acc0[j]);
        acc0[j] = fmaf(u0.y, vB[j], acc0[j]);
        acc0[j] = fmaf(u0.z, vC[j], acc0[j]);
        acc0[j] = fmaf(u0.w, vD[j], acc0[j]);
        acc1[j] = fmaf(u1.x, vA[j], acc1[j]);
        acc1[j] = fmaf(u1.y, vB[j], acc1[j]);
        acc1[j] = fmaf(u1.z, vC[j], acc1[j]);
        acc1[j] = fmaf(u1.w, vD[j], acc1[j]);
        acc2[j] = fmaf(u2.x, vA[j], acc2[j]);
        acc2[j] = fmaf(u2.y, vB[j], acc2[j]);
        acc2[j] = fmaf(u2.z, vC[j], acc2[j]);
        acc2[j] = fmaf(u2.w, vD[j], acc2[j]);
        acc3[j] = fmaf(u3.x, vA[j], acc3[j]);
        acc3[j] = fmaf(u3.y, vB[j], acc3[j]);
        acc3[j] = fmaf(u3.z, vC[j], acc3[j]);
        acc3[j] = fmaf(u3.w, vD[j], acc3[j]);
      }
    }
    __syncthreads();
  }

  int y = y0 + ty;
  float b0 = bias[ob * 4 + 0], b1 = bias[ob * 4 + 1];
  float b2 = bias[ob * 4 + 2], b3 = bias[ob * 4 + 3];
#pragma unroll
  for (int j = 0; j < 4; ++j) {
    int px = tx * 4 + j;
    float v0 = acc0[j] + b0, v1 = acc1[j] + b1, v2 = acc2[j] + b2, v3 = acc3[j] + b3;
    if (y == 127 || px == 127) { v0 = 0.f; v1 = 0.f; v2 = 0.f; v3 = 0.f; }
    ushort4 h;
    h.x = f2b(v0); h.y = f2b(v1); h.z = f2b(v2); h.w = f2b(v3);
    *(ushort4*)(outH + (((size_t)(n * 128 + y)) * 128 + px) * 64 + ob * 4) = h;
  }
}

// ---------------------------------------------------------------------------
extern "C" void kernel_launch(void* const* d_in, const int* in_sizes, int n_in,
                              void* d_out, int out_size, void* d_ws, size_t ws_size,
                              hipStream_t stream) {
  const float* xd = (const float*)d_in[0];
  const float* xl = (const float*)d_in[1];
  const float* xr = (const float*)d_in[2];
  const float* up_w = (const float*)d_in[3];
  const float* up_b = (const float*)d_in[4];
  const float* offl_w = (const float*)d_in[5];
  const float* offl_b = (const float*)d_in[6];
  const float* dl_w = (const float*)d_in[7];
  const float* dl_b = (const float*)d_in[8];
  const float* offr_w = (const float*)d_in[9];
  const float* offr_b = (const float*)d_in[10];
  const float* dr_w = (const float*)d_in[11];
  const float* dr_b = (const float*)d_in[12];
  const float* cv_w = (const float*)d_in[13];
  const float* cv_b = (const float*)d_in[14];
  const float* rb1_w1 = (const float*)d_in[15];
  const float* rb1_w2 = (const float*)d_in[16];
  const float* rb2_w1 = (const float*)d_in[17];
  const float* rb2_w2 = (const float*)d_in[18];
  const float* rb1_b1 = (const float*)d_in[19];
  const float* rb1_b2 = (const float*)d_in[20];
  const float* rb2_b1 = (const float*)d_in[21];
  const float* rb2_b2 = (const float*)d_in[22];

  float* ws = (float*)d_ws;
  float* ol = ws;                  // 884736
  float* orr = ws + 884736;        // 884736
  float* upwt = ws + 1769472;      // 32768
  u16* hb = (u16*)(ws + 1802240);
  u16* xlh = hb;                   // 2097152 each
  u16* xrh = hb + 2097152;
  u16* xdph = hb + 4194304;
  u16* xl2h = hb + 6291456;
  u16* xr2h = hb + 8388608;
  u16* t0h = hb + 10485760;
  u16* t1h = hb + 12582912;
  u16* t2h = hb + 14680064;
  u16* t3h = hb + 16777216;
  u16* wcv = hb + 18874368;        // 110592
  u16* wofl = hb + 18984960;       // 55296
  u16* wofr = hb + 19040256;       // 55296
  u16* wr1a = hb + 19095552;       // 36864
  u16* wr1b = hb + 19132416;
  u16* wr2a = hb + 19169280;
  u16* wr2b = hb + 19206144;
  u16* wdl = hb + 19243008;        // 36864
  u16* wdr = hb + 19279872;        // 36864
  float* outp = (float*)d_out;

  hipLaunchKernelGGL(prep_kernel, dim3(1856), dim3(256), 0, stream,
                     dl_w, dr_w, up_w, cv_w, offl_w, offr_w, rb1_w1, rb1_w2,
                     rb2_w1, rb2_w2, upwt, wdl, wdr, wcv, wofl, wofr, wr1a,
                     wr1b, wr2a, wr2b);
  hipLaunchKernelGGL(cvt_nhwc, dim3(128, 4), dim3(256), 0, stream,
                     xl, xr, xlh, xrh);
  hipLaunchKernelGGL(upconv_t, dim3(16, 16, 2), dim3(256), 0, stream,
                     xd, upwt, up_b, xdph);
  hipLaunchKernelGGL(mfconv, dim3(128, 1, 2), dim3(256), 0, stream,
                     xlh, xrh, xdph, wofl, offl_b, (const u16*)nullptr, ol,
                     (u16*)nullptr, 3, 1, 27, 2);
  hipLaunchKernelGGL(deform_mf, dim3(128, 2), dim3(512), 0, stream,
                     xlh, ol, wdl, dl_b, xl2h);
  hipLaunchKernelGGL(mfconv, dim3(128, 1, 2), dim3(256), 0, stream,
                     xl2h, xrh, xdph, wofr, offr_b, (const u16*)nullptr, orr,
                     (u16*)nullptr, 3, 1, 27, 2);
  hipLaunchKernelGGL(deform_mf, dim3(128, 2), dim3(512), 0, stream,
                     xrh, orr, wdr, dr_b, xr2h);
  hipLaunchKernelGGL(mfconv, dim3(128, 1, 2), dim3(256), 0, stream,
                     xl2h, xr2h, xdph, wcv, cv_b, (const u16*)nullptr,
                     (float*)nullptr, t0h, 3, 2, 64, 1);
  hipLaunchKernelGGL(mfconv, dim3(128, 1, 2), dim3(256), 0, stream,
                     t0h, (const u16*)nullptr, (const u16*)nullptr, wr1a,
                     rb1_b1, (const u16*)nullptr, (float*)nullptr, t1h,
                     1, 2, 64, 1);
  hipLaunchKernelGGL(mfconv, dim3(128, 1, 2), dim3(256), 0, stream,
                     t1h, (const u16*)nullptr, (const u16*)nullptr, wr1b,
                     rb1_b2, t0h, (float*)nullptr, t2h, 1, 2, 64, 3);
  hipLaunchKernelGGL(mfconv, dim3(128, 1, 2), dim3(256), 0, stream,
                     t2h, (const u16*)nullptr, (const u16*)nullptr, wr2a,
                     rb2_b1, (const u16*)nullptr, (float*)nullptr, t3h,
                     1, 2, 64, 1);
  hipLaunchKernelGGL(mfconv, dim3(128, 1, 2), dim3(256), 0, stream,
                     t3h, (const u16*)nullptr, (const u16*)nullptr, wr2b,
                     rb2_b2, t2h, outp, (u16*)nullptr, 1, 2, 64, 3);
}

// Round 6
// 323.617 us; speedup vs baseline: 4.6530x; 1.1403x over previous
//
#include <hip/hip_runtime.h>
#include <math.h>

#define HW 16384

typedef unsigned short u16;
typedef __attribute__((ext_vector_type(8))) short short8;
typedef __attribute__((ext_vector_type(16))) float f32x16;

union U16B {
  uint4 u;
  short8 v;
  u16 s[8];
};

__device__ inline u16 f2b(float f) {
  unsigned u = __float_as_uint(f);
  u += 0x7FFF + ((u >> 16) & 1);
  return (u16)(u >> 16);
}
__device__ inline float b2f(u16 h) {
  return __uint_as_float(((unsigned)h) << 16);
}

// ---------------------------------------------------------------------------
// Prep: pack all weights (bf16 per-lane MFMA A-fragments).
//  - 3x3 convs: wpk[((((s*3+ky)*3+kx)*4+ks)*OT+ot)*512 + lane*8 + j] =
//      w[och=ot*32+(lane&31)][ch=s*64+ks*16+(lane>>5)*8+j][ky*3+kx]
//  - deform: wdk[((k*4+ks)*2+ot)*512 + lane*8 + j] (k = tap)
//  - upconv: wup[((t*8+ks)*2+ot)*512 + lane*8 + j] =
//      w[och][ci=ks*16+(lane>>5)*8+j][t]   (Cin=128 -> ks 0..7, t=ty*2+tx)
// ---------------------------------------------------------------------------
__device__ inline u16 pack_frag(const float* __restrict__ w, int Cin, int O,
                                int OT, int d) {
  int j = d & 7;
  int lane = (d >> 3) & 63;
  int rest = d >> 9;
  int ot = rest % OT; rest /= OT;
  int ks = rest & 3; rest >>= 2;
  int kx = rest % 3; rest /= 3;
  int ky = rest % 3; int s = rest / 3;
  int och = ot * 32 + (lane & 31);
  int ch = s * 64 + ks * 16 + ((lane >> 5) << 3) + j;
  if (och >= O) return 0;
  return f2b(w[((size_t)och * Cin + ch) * 9 + ky * 3 + kx]);
}

__device__ inline u16 pack_def(const float* __restrict__ w, int d) {
  int j = d & 7;
  int lane = (d >> 3) & 63;
  int g = d >> 9;
  int ot = g & 1;
  int t = g >> 1;
  int ks = t & 3;
  int k = t >> 2;
  int och = ot * 32 + (lane & 31);
  int c = ks * 16 + ((lane >> 5) << 3) + j;
  return f2b(w[((size_t)och * 64 + c) * 9 + k]);
}

__device__ inline u16 pack_up(const float* __restrict__ w, int d) {
  int j = d & 7;
  int lane = (d >> 3) & 63;
  int g = d >> 9;
  int ot = g & 1;
  int rest = g >> 1;
  int ks = rest & 7;   // 8 ks groups: ci 0..127
  int t = rest >> 3;
  int och = ot * 32 + (lane & 31);
  int ci = ks * 16 + ((lane >> 5) << 3) + j;
  return f2b(w[((size_t)och * 128 + ci) * 4 + t]);
}

__global__ __launch_bounds__(256) void prep_kernel(
    const float* __restrict__ dl_w, const float* __restrict__ dr_w,
    const float* __restrict__ up_w, const float* __restrict__ cv_w,
    const float* __restrict__ offl_w, const float* __restrict__ offr_w,
    const float* __restrict__ r1a, const float* __restrict__ r1b,
    const float* __restrict__ r2a, const float* __restrict__ r2b,
    u16* __restrict__ wup, u16* __restrict__ wdl, u16* __restrict__ wdr,
    u16* __restrict__ wcv, u16* __restrict__ wofl, u16* __restrict__ wofr,
    u16* __restrict__ wr1a, u16* __restrict__ wr1b,
    u16* __restrict__ wr2a, u16* __restrict__ wr2b) {
  int d = blockIdx.x * 256 + threadIdx.x;
  if (d < 32768) { wup[d] = pack_up(up_w, d); return; }
  d -= 32768;
  if (d < 36864) { wdl[d] = pack_def(dl_w, d); return; }
  d -= 36864;
  if (d < 36864) { wdr[d] = pack_def(dr_w, d); return; }
  d -= 36864;
  if (d < 110592) { wcv[d] = pack_frag(cv_w, 192, 64, 2, d); return; }
  d -= 110592;
  if (d < 55296) { wofl[d] = pack_frag(offl_w, 192, 27, 1, d); return; }
  d -= 55296;
  if (d < 55296) { wofr[d] = pack_frag(offr_w, 192, 27, 1, d); return; }
  d -= 55296;
  if (d < 36864) { wr1a[d] = pack_frag(r1a, 64, 64, 2, d); return; }
  d -= 36864;
  if (d < 36864) { wr1b[d] = pack_frag(r1b, 64, 64, 2, d); return; }
  d -= 36864;
  if (d < 36864) { wr2a[d] = pack_frag(r2a, 64, 64, 2, d); return; }
  d -= 36864;
  if (d < 36864) { wr2b[d] = pack_frag(r2b, 64, 64, 2, d); return; }
}

// ---------------------------------------------------------------------------
// NCHW fp32 -> NHWC bf16 (xl, xr: 64ch 128x128). One row per block.
// ---------------------------------------------------------------------------
__global__ __launch_bounds__(256) void cvt_nhwc(
    const float* __restrict__ xl, const float* __restrict__ xr,
    u16* __restrict__ xlh, u16* __restrict__ xrh) {
  __shared__ float sT[64 * 132];
  int tid = threadIdx.x;
  int y = blockIdx.x;
  int pid = blockIdx.y;
  const float* src = (pid >> 1) ? xr : xl;
  u16* dst = (pid >> 1) ? xrh : xlh;
  int n = pid & 1;
#pragma unroll
  for (int i = 0; i < 8; ++i) {
    int q = tid + i * 256;
    int ch = q >> 5, pxq = q & 31;
    float4 v = *(const float4*)(src + ((size_t)(n * 64 + ch)) * HW + y * 128 + pxq * 4);
    *(float4*)&sT[ch * 132 + pxq * 4] = v;
  }
  __syncthreads();
  int px = tid >> 1, half = tid & 1;
  u16* op = dst + (((size_t)(n * 128 + y)) * 128 + px) * 64 + half * 32;
#pragma unroll
  for (int c = 0; c < 4; ++c) {
    uint4 v;
    int ob = (half * 32 + c * 8);
    v.x = (unsigned)f2b(sT[(ob + 0) * 132 + px]) | ((unsigned)f2b(sT[(ob + 1) * 132 + px]) << 16);
    v.y = (unsigned)f2b(sT[(ob + 2) * 132 + px]) | ((unsigned)f2b(sT[(ob + 3) * 132 + px]) << 16);
    v.z = (unsigned)f2b(sT[(ob + 4) * 132 + px]) | ((unsigned)f2b(sT[(ob + 5) * 132 + px]) << 16);
    v.w = (unsigned)f2b(sT[(ob + 6) * 132 + px]) | ((unsigned)f2b(sT[(ob + 7) * 132 + px]) << 16);
    *(uint4*)(op + c * 8) = v;
  }
}

// ---------------------------------------------------------------------------
// xd NCHW fp32 (N,128,64,64) -> NHWC bf16 [n][row][col][128ch].
// One input row per block.
// ---------------------------------------------------------------------------
__global__ __launch_bounds__(256) void cvt_xd(
    const float* __restrict__ xd, u16* __restrict__ xdh) {
  __shared__ float sT[128 * 66];
  int tid = threadIdx.x;
  int r = blockIdx.x;
  int n = blockIdx.y;
#pragma unroll
  for (int i = 0; i < 8; ++i) {
    int q = tid + i * 256;
    int ch = q >> 4, col4 = q & 15;
    float4 v = *(const float4*)(xd + ((size_t)(n * 128 + ch) * 64 + r) * 64 + col4 * 4);
    *(float4*)&sT[ch * 66 + col4 * 4] = v;
  }
  __syncthreads();
#pragma unroll
  for (int i = 0; i < 4; ++i) {
    int q = tid + i * 256;
    int col = q >> 4, cho = q & 15;
    uint4 v;
    int cb = cho * 8;
    v.x = (unsigned)f2b(sT[(cb + 0) * 66 + col]) | ((unsigned)f2b(sT[(cb + 1) * 66 + col]) << 16);
    v.y = (unsigned)f2b(sT[(cb + 2) * 66 + col]) | ((unsigned)f2b(sT[(cb + 3) * 66 + col]) << 16);
    v.z = (unsigned)f2b(sT[(cb + 4) * 66 + col]) | ((unsigned)f2b(sT[(cb + 5) * 66 + col]) << 16);
    v.w = (unsigned)f2b(sT[(cb + 6) * 66 + col]) | ((unsigned)f2b(sT[(cb + 7) * 66 + col]) << 16);
    *(uint4*)(xdh + (((size_t)(n * 64 + r)) * 64 + col) * 128 + cb) = v;
  }
}

// ---------------------------------------------------------------------------
// Fused nearest-x2 upsample + 2x2 conv + zero-pad via gather + MFMA.
// out[och][px] = sum_t sum_ci w[och][ci][t] * xd[(y+ty)>>1][(px+tx)>>1][ci]
// Block = one out row (128 px), 512 thr = 8 waves = 4 px-tiles x 2 tap-halves.
// Cin=128 -> 8 ks-groups of 16 per tap.
// ---------------------------------------------------------------------------
__global__ __launch_bounds__(512) void upconv_mf(
    const u16* __restrict__ xdh, const u16* __restrict__ wup,
    const float* __restrict__ bias, u16* __restrict__ outH) {
  __shared__ float s_red[4][2][16][64];
  const int tid = threadIdx.x;
  const int lane = tid & 63;
  const int w = tid >> 6;
  const int p2 = w >> 1;
  const int th = w & 1;
  const int y = blockIdx.x;
  const int n = blockIdx.y;
  const int px = (p2 << 5) + (lane & 31);
  const int h = lane >> 5;

  f32x16 acc0, acc1;
#pragma unroll
  for (int i = 0; i < 16; ++i) { acc0[i] = 0.f; acc1[i] = 0.f; }

  const u16* xb = xdh + ((size_t)n * 64 * 64) * 128;

#pragma unroll
  for (int tt = 0; tt < 2; ++tt) {
    const int t = th * 2 + tt;
    const int ty = t >> 1, tx = t & 1;
    const int row = min((y + ty) >> 1, 63);
    const int col = min((px + tx) >> 1, 63);
    const u16* src = xb + ((size_t)(row * 64 + col)) * 128;
#pragma unroll
    for (int ks = 0; ks < 8; ++ks) {
      U16B bf;
      bf.u = *(const uint4*)(src + ks * 16 + h * 8);
      const u16* wp = wup + ((size_t)((t * 8 + ks) * 2)) * 512 + lane * 8;
      U16B a0, a1;
      a0.u = *(const uint4*)wp;
      a1.u = *(const uint4*)(wp + 512);
      acc0 = __builtin_amdgcn_mfma_f32_32x32x16_bf16(a0.v, bf.v, acc0, 0, 0, 0);
      acc1 = __builtin_amdgcn_mfma_f32_32x32x16_bf16(a1.v, bf.v, acc1, 0, 0, 0);
    }
  }

  if (th == 1) {
#pragma unroll
    for (int i = 0; i < 16; ++i) {
      s_red[p2][0][i][lane] = acc0[i];
      s_red[p2][1][i][lane] = acc1[i];
    }
  }
  __syncthreads();
  if (th == 0) {
    const bool zero = (y == 127) || (px == 127);
    const size_t pixb = (((size_t)(n * 128 + y)) * 128 + px) * 64;
#pragma unroll
    for (int ot = 0; ot < 2; ++ot) {
      f32x16 A = ot ? acc1 : acc0;
#pragma unroll
      for (int q = 0; q < 4; ++q) {
        int oo = ot * 32 + 8 * q + 4 * h;
        float v[4];
#pragma unroll
        for (int r = 0; r < 4; ++r)
          v[r] = zero ? 0.f : (A[q * 4 + r] + s_red[p2][ot][q * 4 + r][lane] + bias[oo + r]);
        ushort4 hh;
        hh.x = f2b(v[0]); hh.y = f2b(v[1]); hh.z = f2b(v[2]); hh.w = f2b(v[3]);
        *(ushort4*)(outH + pixb + oo) = hh;
      }
    }
  }
}

// ---------------------------------------------------------------------------
// MFMA 3x3 conv, pad=1, inputs NHWC bf16 (up to 3 concatenated 64-ch segs).
// (unchanged — validated)
// ---------------------------------------------------------------------------
__global__ __launch_bounds__(256) void mfconv(
    const u16* __restrict__ in0, const u16* __restrict__ in1,
    const u16* __restrict__ in2, const u16* __restrict__ wpk,
    const float* __restrict__ bias, const u16* __restrict__ resh,
    float* __restrict__ outF, u16* __restrict__ outH,
    int nseg, int OT, int O, int mode) {
  __shared__ __align__(16) u16 sx[2][8 * 130 * 8];
  const int tid = threadIdx.x;
  const int lane = tid & 63;
  const int w = tid >> 6;
  const int y = blockIdx.x;
  const int n = blockIdx.z;

  if (tid < 32) {
    int b = tid >> 4, e = (tid >> 3) & 1, cg = tid & 7;
    uint4 z = make_uint4(0, 0, 0, 0);
    *(uint4*)&sx[b][(cg * 130 + (e ? 129 : 0)) * 8] = z;
  }

  auto stage = [&](int buf, const u16* src, int row) {
#pragma unroll
    for (int i = 0; i < 4; ++i) {
      int q = tid + i * 256;
      int px = q >> 3, cg = q & 7;
      uint4 v = *(const uint4*)(src + (((size_t)(n * 128 + row)) * 128 + px) * 64 + cg * 8);
      *(uint4*)&sx[buf][(cg * 130 + px + 1) * 8] = v;
    }
  };

  f32x16 acc0, acc1;
#pragma unroll
  for (int i = 0; i < 16; ++i) { acc0[i] = 0.f; acc1[i] = 0.f; }

  const int kylo = (y == 0) ? 1 : 0;
  const int kyhi = (y == 127) ? 1 : 2;
  const int nky = kyhi - kylo + 1;
  const int ni = nseg * nky;
  const int pxb = (w << 5) + (lane & 31);
  const int hb = lane >> 5;

  stage(0, in0, y + kylo - 1);
  int cur = 0;
  for (int i = 0; i < ni; ++i) {
    int s = i / nky, ky = kylo + (i % nky);
    __syncthreads();
    if (i + 1 < ni) {
      int i2 = i + 1;
      int s2 = i2 / nky, ky2 = kylo + (i2 % nky);
      const u16* sp = (s2 == 0) ? in0 : ((s2 == 1) ? in1 : in2);
      stage(cur ^ 1, sp, y + ky2 - 1);
    }
    const u16* wb = wpk + (size_t)(s * 3 + ky) * 3 * 4 * OT * 512;
#pragma unroll
    for (int kx = 0; kx < 3; ++kx) {
#pragma unroll
      for (int ks = 0; ks < 4; ++ks) {
        U16B bf;
        bf.u = *(const uint4*)&sx[cur][((ks * 2 + hb) * 130 + pxb + kx) * 8];
        const u16* wp = wb + ((size_t)(kx * 4 + ks) * OT) * 512 + lane * 8;
        U16B a0;
        a0.u = *(const uint4*)wp;
        acc0 = __builtin_amdgcn_mfma_f32_32x32x16_bf16(a0.v, bf.v, acc0, 0, 0, 0);
        if (OT == 2) {
          U16B a1;
          a1.u = *(const uint4*)(wp + 512);
          acc1 = __builtin_amdgcn_mfma_f32_32x32x16_bf16(a1.v, bf.v, acc1, 0, 0, 0);
        }
      }
    }
    cur ^= 1;
  }

  const size_t pixbase = ((size_t)(n * 128 + y)) * 128 + pxb;
  if (outH) {
#pragma unroll
    for (int ot = 0; ot < 2; ++ot) {
      if (ot >= OT) break;
      f32x16 A = (ot == 0) ? acc0 : acc1;
#pragma unroll
      for (int q = 0; q < 4; ++q) {
        int oo = ot * 32 + 8 * q + 4 * hb;
        float v[4];
#pragma unroll
        for (int r = 0; r < 4; ++r) v[r] = A[q * 4 + r] + bias[oo + r];
        if (mode == 1) {
#pragma unroll
          for (int r = 0; r < 4; ++r) v[r] = fmaxf(v[r], 0.f);
        } else if (mode == 3) {
          ushort4 rv = *(const ushort4*)(resh + pixbase * 64 + oo);
          v[0] += b2f(rv.x); v[1] += b2f(rv.y); v[2] += b2f(rv.z); v[3] += b2f(rv.w);
        }
        ushort4 h;
        h.x = f2b(v[0]); h.y = f2b(v[1]); h.z = f2b(v[2]); h.w = f2b(v[3]);
        *(ushort4*)(outH + pixbase * 64 + oo) = h;
      }
    }
  } else {
#pragma unroll
    for (int ot = 0; ot < 2; ++ot) {
      if (ot >= OT) break;
      f32x16 A = (ot == 0) ? acc0 : acc1;
#pragma unroll
      for (int q = 0; q < 4; ++q) {
        int oo = ot * 32 + 8 * q + 4 * hb;
#pragma unroll
        for (int r = 0; r < 4; ++r) {
          int och = oo + r;
          if (och >= O) continue;
          float v = A[q * 4 + r] + bias[och];
          if (mode == 2) {
            if (och >= 18) v = 1.f / (1.f + expf(-v));
          } else if (mode == 3) {
            v += b2f(resh[pixbase * 64 + och]);
          }
          outF[((size_t)(n * O + och)) * HW + y * 128 + pxb] = v;
        }
      }
    }
  }
}

// ---------------------------------------------------------------------------
// Modulated deformable conv 3x3 via gather + MFMA (unchanged — validated).
// ---------------------------------------------------------------------------
__global__ __launch_bounds__(512) void deform_mf(
    const u16* __restrict__ xh, const float* __restrict__ offm,
    const u16* __restrict__ wpk, const float* __restrict__ bias,
    u16* __restrict__ outH) {
  __shared__ float s_off[27][128];
  __shared__ float s_red[4][2][16][64];
  const int tid = threadIdx.x;
  const int lane = tid & 63;
  const int w = tid >> 6;
  const int p2 = w >> 1;
  const int kh = w & 1;
  const int y = blockIdx.x;
  const int n = blockIdx.y;
  const int px = (p2 << 5) + (lane & 31);
  const int h = lane >> 5;

  for (int idx = tid; idx < 27 * 128; idx += 512) {
    int ch = idx >> 7, pp = idx & 127;
    s_off[ch][pp] = offm[((size_t)(n * 27 + ch) * 128 + y) * 128 + pp];
  }
  __syncthreads();

  f32x16 acc0, acc1;
#pragma unroll
  for (int i = 0; i < 16; ++i) { acc0[i] = 0.f; acc1[i] = 0.f; }

  const u16* xb = xh + ((size_t)n * HW) * 64;

#pragma unroll
  for (int kk = 0; kk < 5; ++kk) {
    if (kh && kk == 4) break;
    const int k = kh * 5 + kk;
    const int ky = k / 3 - 1, kx = k % 3 - 1;
    float dy = s_off[2 * k][px];
    float dx = s_off[2 * k + 1][px];
    float m = s_off[18 + k][px];
    float py = dy + (float)(y + ky);
    float pxf = dx + (float)(px + kx);
    float fy = floorf(py), fxx = floorf(pxf);
    float wy = py - fy, wx = pxf - fxx;
    int iy0 = (int)fy, ix0 = (int)fxx;
    bool vy0 = (unsigned)iy0 < 128u, vy1 = (unsigned)(iy0 + 1) < 128u;
    bool vx0 = (unsigned)ix0 < 128u, vx1 = (unsigned)(ix0 + 1) < 128u;
    float omwy = 1.f - wy, omwx = 1.f - wx;
    float f00 = (vy0 && vx0) ? omwy * omwx * m : 0.f;
    float f01 = (vy0 && vx1) ? omwy * wx * m : 0.f;
    float f10 = (vy1 && vx0) ? wy * omwx * m : 0.f;
    float f11 = (vy1 && vx1) ? wy * wx * m : 0.f;
    int y0c = min(max(iy0, 0), 127), y1c = min(max(iy0 + 1, 0), 127);
    int x0c = min(max(ix0, 0), 127), x1c = min(max(ix0 + 1, 0), 127);
    const u16* r00 = xb + ((size_t)(y0c * 128 + x0c)) * 64;
    const u16* r01 = xb + ((size_t)(y0c * 128 + x1c)) * 64;
    const u16* r10 = xb + ((size_t)(y1c * 128 + x0c)) * 64;
    const u16* r11 = xb + ((size_t)(y1c * 128 + x1c)) * 64;
#pragma unroll
    for (int ks = 0; ks < 4; ++ks) {
      const int co = ks * 16 + h * 8;
      U16B u00, u01, u10, u11;
      u00.u = *(const uint4*)(r00 + co);
      u01.u = *(const uint4*)(r01 + co);
      u10.u = *(const uint4*)(r10 + co);
      u11.u = *(const uint4*)(r11 + co);
      unsigned dw[4];
#pragma unroll
      for (int jj = 0; jj < 4; ++jj) {
        float s0 = f00 * b2f(u00.s[2 * jj]) + f01 * b2f(u01.s[2 * jj]) +
                   f10 * b2f(u10.s[2 * jj]) + f11 * b2f(u11.s[2 * jj]);
        float s1 = f00 * b2f(u00.s[2 * jj + 1]) + f01 * b2f(u01.s[2 * jj + 1]) +
                   f10 * b2f(u10.s[2 * jj + 1]) + f11 * b2f(u11.s[2 * jj + 1]);
        dw[jj] = (unsigned)f2b(s0) | ((unsigned)f2b(s1) << 16);
      }
      U16B bf;
      bf.u = make_uint4(dw[0], dw[1], dw[2], dw[3]);
      const u16* wp = wpk + ((size_t)((k * 4 + ks) * 2)) * 512 + lane * 8;
      U16B a0, a1;
      a0.u = *(const uint4*)wp;
      a1.u = *(const uint4*)(wp + 512);
      acc0 = __builtin_amdgcn_mfma_f32_32x32x16_bf16(a0.v, bf.v, acc0, 0, 0, 0);
      acc1 = __builtin_amdgcn_mfma_f32_32x32x16_bf16(a1.v, bf.v, acc1, 0, 0, 0);
    }
  }

  if (kh == 1) {
#pragma unroll
    for (int i = 0; i < 16; ++i) {
      s_red[p2][0][i][lane] = acc0[i];
      s_red[p2][1][i][lane] = acc1[i];
    }
  }
  __syncthreads();
  if (kh == 0) {
    const size_t pixb = (((size_t)(n * 128 + y)) * 128 + px) * 64;
#pragma unroll
    for (int ot = 0; ot < 2; ++ot) {
      f32x16 A = ot ? acc1 : acc0;
#pragma unroll
      for (int q = 0; q < 4; ++q) {
        int oo = ot * 32 + 8 * q + 4 * h;
        float v[4];
#pragma unroll
        for (int r = 0; r < 4; ++r)
          v[r] = A[q * 4 + r] + s_red[p2][ot][q * 4 + r][lane] + bias[oo + r];
        ushort4 hh;
        hh.x = f2b(v[0]); hh.y = f2b(v[1]); hh.z = f2b(v[2]); hh.w = f2b(v[3]);
        *(ushort4*)(outH + pixb + oo) = hh;
      }
    }
  }
}

// ---------------------------------------------------------------------------
extern "C" void kernel_launch(void* const* d_in, const int* in_sizes, int n_in,
                              void* d_out, int out_size, void* d_ws, size_t ws_size,
                              hipStream_t stream) {
  const float* xd = (const float*)d_in[0];
  const float* xl = (const float*)d_in[1];
  const float* xr = (const float*)d_in[2];
  const float* up_w = (const float*)d_in[3];
  const float* up_b = (const float*)d_in[4];
  const float* offl_w = (const float*)d_in[5];
  const float* offl_b = (const float*)d_in[6];
  const float* dl_w = (const float*)d_in[7];
  const float* dl_b = (const float*)d_in[8];
  const float* offr_w = (const float*)d_in[9];
  const float* offr_b = (const float*)d_in[10];
  const float* dr_w = (const float*)d_in[11];
  const float* dr_b = (const float*)d_in[12];
  const float* cv_w = (const float*)d_in[13];
  const float* cv_b = (const float*)d_in[14];
  const float* rb1_w1 = (const float*)d_in[15];
  const float* rb1_w2 = (const float*)d_in[16];
  const float* rb2_w1 = (const float*)d_in[17];
  const float* rb2_w2 = (const float*)d_in[18];
  const float* rb1_b1 = (const float*)d_in[19];
  const float* rb1_b2 = (const float*)d_in[20];
  const float* rb2_b1 = (const float*)d_in[21];
  const float* rb2_b2 = (const float*)d_in[22];

  float* ws = (float*)d_ws;
  float* ol = ws;                  // 884736
  float* orr = ws + 884736;        // 884736
  u16* hb = (u16*)(ws + 1769472);
  u16* xlh = hb;                   // 2097152 each
  u16* xrh = hb + 2097152;
  u16* xdph = hb + 4194304;
  u16* xl2h = hb + 6291456;
  u16* xr2h = hb + 8388608;
  u16* t0h = hb + 10485760;
  u16* t1h = hb + 12582912;
  u16* t2h = hb + 14680064;
  u16* t3h = hb + 16777216;
  u16* xdh = hb + 18874368;        // 1048576 (2*64*64*128)
  u16* wcv = hb + 19922944;        // 110592
  u16* wofl = hb + 20033536;       // 55296
  u16* wofr = hb + 20088832;       // 55296
  u16* wr1a = hb + 20144128;       // 36864
  u16* wr1b = hb + 20180992;
  u16* wr2a = hb + 20217856;
  u16* wr2b = hb + 20254720;
  u16* wdl = hb + 20291584;        // 36864
  u16* wdr = hb + 20328448;        // 36864
  u16* wup = hb + 20365312;        // 32768
  float* outp = (float*)d_out;

  hipLaunchKernelGGL(prep_kernel, dim3(1856), dim3(256), 0, stream,
                     dl_w, dr_w, up_w, cv_w, offl_w, offr_w, rb1_w1, rb1_w2,
                     rb2_w1, rb2_w2, wup, wdl, wdr, wcv, wofl, wofr, wr1a,
                     wr1b, wr2a, wr2b);
  hipLaunchKernelGGL(cvt_nhwc, dim3(128, 4), dim3(256), 0, stream,
                     xl, xr, xlh, xrh);
  hipLaunchKernelGGL(cvt_xd, dim3(64, 2), dim3(256), 0, stream,
                     xd, xdh);
  hipLaunchKernelGGL(upconv_mf, dim3(128, 2), dim3(512), 0, stream,
                     xdh, wup, up_b, xdph);
  hipLaunchKernelGGL(mfconv, dim3(128, 1, 2), dim3(256), 0, stream,
                     xlh, xrh, xdph, wofl, offl_b, (const u16*)nullptr, ol,
                     (u16*)nullptr, 3, 1, 27, 2);
  hipLaunchKernelGGL(deform_mf, dim3(128, 2), dim3(512), 0, stream,
                     xlh, ol, wdl, dl_b, xl2h);
  hipLaunchKernelGGL(mfconv, dim3(128, 1, 2), dim3(256), 0, stream,
                     xl2h, xrh, xdph, wofr, offr_b, (const u16*)nullptr, orr,
                     (u16*)nullptr, 3, 1, 27, 2);
  hipLaunchKernelGGL(deform_mf, dim3(128, 2), dim3(512), 0, stream,
                     xrh, orr, wdr, dr_b, xr2h);
  hipLaunchKernelGGL(mfconv, dim3(128, 1, 2), dim3(256), 0, stream,
                     xl2h, xr2h, xdph, wcv, cv_b, (const u16*)nullptr,
                     (float*)nullptr, t0h, 3, 2, 64, 1);
  hipLaunchKernelGGL(mfconv, dim3(128, 1, 2), dim3(256), 0, stream,
                     t0h, (const u16*)nullptr, (const u16*)nullptr, wr1a,
                     rb1_b1, (const u16*)nullptr, (float*)nullptr, t1h,
                     1, 2, 64, 1);
  hipLaunchKernelGGL(mfconv, dim3(128, 1, 2), dim3(256), 0, stream,
                     t1h, (const u16*)nullptr, (const u16*)nullptr, wr1b,
                     rb1_b2, t0h, (float*)nullptr, t2h, 1, 2, 64, 3);
  hipLaunchKernelGGL(mfconv, dim3(128, 1, 2), dim3(256), 0, stream,
                     t2h, (const u16*)nullptr, (const u16*)nullptr, wr2a,
                     rb2_b1, (const u16*)nullptr, (float*)nullptr, t3h,
                     1, 2, 64, 1);
  hipLaunchKernelGGL(mfconv, dim3(128, 1, 2), dim3(256), 0, stream,
                     t3h, (const u16*)nullptr, (const u16*)nullptr, wr2b,
                     rb2_b2, t2h, outp, (u16*)nullptr, 1, 2, 64, 3);
}

// Round 7
// 214.094 us; speedup vs baseline: 7.0333x; 1.5116x over previous
//
#include <hip/hip_runtime.h>
#include <math.h>

#define HW 16384

typedef unsigned short u16;
typedef __attribute__((ext_vector_type(8))) short short8;
typedef __attribute__((ext_vector_type(16))) float f32x16;

union U16B {
  uint4 u;
  short8 v;
  u16 s[8];
};

__device__ inline u16 f2b(float f) {
  unsigned u = __float_as_uint(f);
  u += 0x7FFF + ((u >> 16) & 1);
  return (u16)(u >> 16);
}
__device__ inline float b2f(u16 h) {
  return __uint_as_float(((unsigned)h) << 16);
}

// ---------------------------------------------------------------------------
// Prep: pack all weights (bf16 per-lane MFMA A-fragments).
//  - 3x3 convs: wpk[((((s*3+ky)*3+kx)*4+ks)*OT+ot)*512 + lane*8 + j] =
//      w[och=ot*32+(lane&31)][ch=s*64+ks*16+(lane>>5)*8+j][ky*3+kx]
//  - deform: wdk[((k*4+ks)*2+ot)*512 + lane*8 + j] (k = tap)
//  - upconv: wup[((t*8+ks)*2+ot)*512 + lane*8 + j] (Cin=128 -> ks 0..7)
// ---------------------------------------------------------------------------
__device__ inline u16 pack_frag(const float* __restrict__ w, int Cin, int O,
                                int OT, int d) {
  int j = d & 7;
  int lane = (d >> 3) & 63;
  int rest = d >> 9;
  int ot = rest % OT; rest /= OT;
  int ks = rest & 3; rest >>= 2;
  int kx = rest % 3; rest /= 3;
  int ky = rest % 3; int s = rest / 3;
  int och = ot * 32 + (lane & 31);
  int ch = s * 64 + ks * 16 + ((lane >> 5) << 3) + j;
  if (och >= O) return 0;
  return f2b(w[((size_t)och * Cin + ch) * 9 + ky * 3 + kx]);
}

__device__ inline u16 pack_def(const float* __restrict__ w, int d) {
  int j = d & 7;
  int lane = (d >> 3) & 63;
  int g = d >> 9;
  int ot = g & 1;
  int t = g >> 1;
  int ks = t & 3;
  int k = t >> 2;
  int och = ot * 32 + (lane & 31);
  int c = ks * 16 + ((lane >> 5) << 3) + j;
  return f2b(w[((size_t)och * 64 + c) * 9 + k]);
}

__device__ inline u16 pack_up(const float* __restrict__ w, int d) {
  int j = d & 7;
  int lane = (d >> 3) & 63;
  int g = d >> 9;
  int ot = g & 1;
  int rest = g >> 1;
  int ks = rest & 7;
  int t = rest >> 3;
  int och = ot * 32 + (lane & 31);
  int ci = ks * 16 + ((lane >> 5) << 3) + j;
  return f2b(w[((size_t)och * 128 + ci) * 4 + t]);
}

__global__ __launch_bounds__(256) void prep_kernel(
    const float* __restrict__ dl_w, const float* __restrict__ dr_w,
    const float* __restrict__ up_w, const float* __restrict__ cv_w,
    const float* __restrict__ offl_w, const float* __restrict__ offr_w,
    const float* __restrict__ r1a, const float* __restrict__ r1b,
    const float* __restrict__ r2a, const float* __restrict__ r2b,
    u16* __restrict__ wup, u16* __restrict__ wdl, u16* __restrict__ wdr,
    u16* __restrict__ wcv, u16* __restrict__ wofl, u16* __restrict__ wofr,
    u16* __restrict__ wr1a, u16* __restrict__ wr1b,
    u16* __restrict__ wr2a, u16* __restrict__ wr2b) {
  int d = blockIdx.x * 256 + threadIdx.x;
  if (d < 32768) { wup[d] = pack_up(up_w, d); return; }
  d -= 32768;
  if (d < 36864) { wdl[d] = pack_def(dl_w, d); return; }
  d -= 36864;
  if (d < 36864) { wdr[d] = pack_def(dr_w, d); return; }
  d -= 36864;
  if (d < 110592) { wcv[d] = pack_frag(cv_w, 192, 64, 2, d); return; }
  d -= 110592;
  if (d < 55296) { wofl[d] = pack_frag(offl_w, 192, 27, 1, d); return; }
  d -= 55296;
  if (d < 55296) { wofr[d] = pack_frag(offr_w, 192, 27, 1, d); return; }
  d -= 55296;
  if (d < 36864) { wr1a[d] = pack_frag(r1a, 64, 64, 2, d); return; }
  d -= 36864;
  if (d < 36864) { wr1b[d] = pack_frag(r1b, 64, 64, 2, d); return; }
  d -= 36864;
  if (d < 36864) { wr2a[d] = pack_frag(r2a, 64, 64, 2, d); return; }
  d -= 36864;
  if (d < 36864) { wr2b[d] = pack_frag(r2b, 64, 64, 2, d); return; }
}

// ---------------------------------------------------------------------------
// NCHW fp32 -> NHWC bf16 (xl, xr: 64ch 128x128). One row per block.
// ---------------------------------------------------------------------------
__global__ __launch_bounds__(256) void cvt_nhwc(
    const float* __restrict__ xl, const float* __restrict__ xr,
    u16* __restrict__ xlh, u16* __restrict__ xrh) {
  __shared__ float sT[64 * 132];
  int tid = threadIdx.x;
  int y = blockIdx.x;
  int pid = blockIdx.y;
  const float* src = (pid >> 1) ? xr : xl;
  u16* dst = (pid >> 1) ? xrh : xlh;
  int n = pid & 1;
#pragma unroll
  for (int i = 0; i < 8; ++i) {
    int q = tid + i * 256;
    int ch = q >> 5, pxq = q & 31;
    float4 v = *(const float4*)(src + ((size_t)(n * 64 + ch)) * HW + y * 128 + pxq * 4);
    *(float4*)&sT[ch * 132 + pxq * 4] = v;
  }
  __syncthreads();
  int px = tid >> 1, half = tid & 1;
  u16* op = dst + (((size_t)(n * 128 + y)) * 128 + px) * 64 + half * 32;
#pragma unroll
  for (int c = 0; c < 4; ++c) {
    uint4 v;
    int ob = (half * 32 + c * 8);
    v.x = (unsigned)f2b(sT[(ob + 0) * 132 + px]) | ((unsigned)f2b(sT[(ob + 1) * 132 + px]) << 16);
    v.y = (unsigned)f2b(sT[(ob + 2) * 132 + px]) | ((unsigned)f2b(sT[(ob + 3) * 132 + px]) << 16);
    v.z = (unsigned)f2b(sT[(ob + 4) * 132 + px]) | ((unsigned)f2b(sT[(ob + 5) * 132 + px]) << 16);
    v.w = (unsigned)f2b(sT[(ob + 6) * 132 + px]) | ((unsigned)f2b(sT[(ob + 7) * 132 + px]) << 16);
    *(uint4*)(op + c * 8) = v;
  }
}

// ---------------------------------------------------------------------------
// xd NCHW fp32 (N,128,64,64) -> NHWC bf16 [n][row][col][128ch].
// ---------------------------------------------------------------------------
__global__ __launch_bounds__(256) void cvt_xd(
    const float* __restrict__ xd, u16* __restrict__ xdh) {
  __shared__ float sT[128 * 66];
  int tid = threadIdx.x;
  int r = blockIdx.x;
  int n = blockIdx.y;
#pragma unroll
  for (int i = 0; i < 8; ++i) {
    int q = tid + i * 256;
    int ch = q >> 4, col4 = q & 15;
    float4 v = *(const float4*)(xd + ((size_t)(n * 128 + ch) * 64 + r) * 64 + col4 * 4);
    *(float4*)&sT[ch * 66 + col4 * 4] = v;
  }
  __syncthreads();
#pragma unroll
  for (int i = 0; i < 4; ++i) {
    int q = tid + i * 256;
    int col = q >> 4, cho = q & 15;
    uint4 v;
    int cb = cho * 8;
    v.x = (unsigned)f2b(sT[(cb + 0) * 66 + col]) | ((unsigned)f2b(sT[(cb + 1) * 66 + col]) << 16);
    v.y = (unsigned)f2b(sT[(cb + 2) * 66 + col]) | ((unsigned)f2b(sT[(cb + 3) * 66 + col]) << 16);
    v.z = (unsigned)f2b(sT[(cb + 4) * 66 + col]) | ((unsigned)f2b(sT[(cb + 5) * 66 + col]) << 16);
    v.w = (unsigned)f2b(sT[(cb + 6) * 66 + col]) | ((unsigned)f2b(sT[(cb + 7) * 66 + col]) << 16);
    *(uint4*)(xdh + (((size_t)(n * 64 + r)) * 64 + col) * 128 + cb) = v;
  }
}

// ---------------------------------------------------------------------------
// Fused nearest-x2 upsample + 2x2 conv + zero-pad via gather + MFMA.
// (unchanged — validated in R6)
// ---------------------------------------------------------------------------
__global__ __launch_bounds__(512) void upconv_mf(
    const u16* __restrict__ xdh, const u16* __restrict__ wup,
    const float* __restrict__ bias, u16* __restrict__ outH) {
  __shared__ float s_red[4][2][16][64];
  const int tid = threadIdx.x;
  const int lane = tid & 63;
  const int w = tid >> 6;
  const int p2 = w >> 1;
  const int th = w & 1;
  const int y = blockIdx.x;
  const int n = blockIdx.y;
  const int px = (p2 << 5) + (lane & 31);
  const int h = lane >> 5;

  f32x16 acc0, acc1;
#pragma unroll
  for (int i = 0; i < 16; ++i) { acc0[i] = 0.f; acc1[i] = 0.f; }

  const u16* xb = xdh + ((size_t)n * 64 * 64) * 128;

#pragma unroll
  for (int tt = 0; tt < 2; ++tt) {
    const int t = th * 2 + tt;
    const int ty = t >> 1, tx = t & 1;
    const int row = min((y + ty) >> 1, 63);
    const int col = min((px + tx) >> 1, 63);
    const u16* src = xb + ((size_t)(row * 64 + col)) * 128;
#pragma unroll
    for (int ks = 0; ks < 8; ++ks) {
      U16B bf;
      bf.u = *(const uint4*)(src + ks * 16 + h * 8);
      const u16* wp = wup + ((size_t)((t * 8 + ks) * 2)) * 512 + lane * 8;
      U16B a0, a1;
      a0.u = *(const uint4*)wp;
      a1.u = *(const uint4*)(wp + 512);
      acc0 = __builtin_amdgcn_mfma_f32_32x32x16_bf16(a0.v, bf.v, acc0, 0, 0, 0);
      acc1 = __builtin_amdgcn_mfma_f32_32x32x16_bf16(a1.v, bf.v, acc1, 0, 0, 0);
    }
  }

  if (th == 1) {
#pragma unroll
    for (int i = 0; i < 16; ++i) {
      s_red[p2][0][i][lane] = acc0[i];
      s_red[p2][1][i][lane] = acc1[i];
    }
  }
  __syncthreads();
  if (th == 0) {
    const bool zero = (y == 127) || (px == 127);
    const size_t pixb = (((size_t)(n * 128 + y)) * 128 + px) * 64;
#pragma unroll
    for (int ot = 0; ot < 2; ++ot) {
      f32x16 A = ot ? acc1 : acc0;
#pragma unroll
      for (int q = 0; q < 4; ++q) {
        int oo = ot * 32 + 8 * q + 4 * h;
        float v[4];
#pragma unroll
        for (int r = 0; r < 4; ++r)
          v[r] = zero ? 0.f : (A[q * 4 + r] + s_red[p2][ot][q * 4 + r][lane] + bias[oo + r]);
        ushort4 hh;
        hh.x = f2b(v[0]); hh.y = f2b(v[1]); hh.z = f2b(v[2]); hh.w = f2b(v[3]);
        *(ushort4*)(outH + pixb + oo) = hh;
      }
    }
  }
}

// ---------------------------------------------------------------------------
// MFMA 3x3 conv, pad=1, direct-global-load version (no LDS staging, no
// main-loop barriers). Inputs NHWC bf16 (up to 3 concatenated 64-ch segs).
// Block = one out row, 512 thr = 8 waves = 4 px-tiles x 2 ks-halves.
// grid.y = ot (och tile of 32). K-halves combined via one LDS reduce.
// mode: 1=relu (bf16 out), 2=sigmoid och>=18 (fp32 NCHW out), 3=+residual
// ---------------------------------------------------------------------------
template <int NSEG>
__global__ __launch_bounds__(512) void mfconv_d(
    const u16* __restrict__ in0, const u16* __restrict__ in1,
    const u16* __restrict__ in2, const u16* __restrict__ wpk,
    const float* __restrict__ bias, const u16* __restrict__ resh,
    float* __restrict__ outF, u16* __restrict__ outH,
    int OT, int O, int mode) {
  __shared__ float s_red[4][16][64];
  const int tid = threadIdx.x;
  const int lane = tid & 63;
  const int w = tid >> 6;
  const int p2 = w >> 1;
  const int kh = w & 1;
  const int y = blockIdx.x;
  const int ot = blockIdx.y;
  const int n = blockIdx.z;
  const int px = (p2 << 5) + (lane & 31);
  const int h = lane >> 5;

  f32x16 acc;
#pragma unroll
  for (int i = 0; i < 16; ++i) acc[i] = 0.f;

#pragma unroll
  for (int s = 0; s < NSEG; ++s) {
    const u16* sp = (s == 0) ? in0 : ((s == 1) ? in1 : in2);
    const u16* bn = sp + ((size_t)n * 128) * 128 * 64;
#pragma unroll
    for (int ky = 0; ky < 3; ++ky) {
      int r = y + ky - 1;
      if ((unsigned)r >= 128u) continue;
      const u16* rp = bn + (size_t)r * (128 * 64);
#pragma unroll
      for (int kx = 0; kx < 3; ++kx) {
        int col = px + kx - 1;
        bool valid = (unsigned)col < 128u;
        int colc = min(max(col, 0), 127);
        const u16* pp = rp + (size_t)colc * 64 + h * 8;
#pragma unroll
        for (int k2 = 0; k2 < 2; ++k2) {
          int ks = kh * 2 + k2;
          U16B bf;
          bf.u = *(const uint4*)(pp + ks * 16);
          if (!valid) bf.u = make_uint4(0, 0, 0, 0);
          U16B a;
          a.u = *(const uint4*)(wpk +
                ((size_t)((((s * 3 + ky) * 3 + kx) * 4 + ks) * OT + ot)) * 512 +
                lane * 8);
          acc = __builtin_amdgcn_mfma_f32_32x32x16_bf16(a.v, bf.v, acc, 0, 0, 0);
        }
      }
    }
  }

  if (kh == 1) {
#pragma unroll
    for (int i = 0; i < 16; ++i) s_red[p2][i][lane] = acc[i];
  }
  __syncthreads();
  if (kh == 0) {
    const size_t pixb = ((size_t)(n * 128 + y)) * 128 + px;
    if (outH) {
#pragma unroll
      for (int q = 0; q < 4; ++q) {
        int oo = ot * 32 + 8 * q + 4 * h;
        float v[4];
#pragma unroll
        for (int r = 0; r < 4; ++r)
          v[r] = acc[q * 4 + r] + s_red[p2][q * 4 + r][lane] + bias[oo + r];
        if (mode == 1) {
#pragma unroll
          for (int r = 0; r < 4; ++r) v[r] = fmaxf(v[r], 0.f);
        } else if (mode == 3) {
          ushort4 rv = *(const ushort4*)(resh + pixb * 64 + oo);
          v[0] += b2f(rv.x); v[1] += b2f(rv.y); v[2] += b2f(rv.z); v[3] += b2f(rv.w);
        }
        ushort4 hh;
        hh.x = f2b(v[0]); hh.y = f2b(v[1]); hh.z = f2b(v[2]); hh.w = f2b(v[3]);
        *(ushort4*)(outH + pixb * 64 + oo) = hh;
      }
    } else {
#pragma unroll
      for (int q = 0; q < 4; ++q) {
        int oo = ot * 32 + 8 * q + 4 * h;
#pragma unroll
        for (int r = 0; r < 4; ++r) {
          int och = oo + r;
          if (och >= O) continue;
          float v = acc[q * 4 + r] + s_red[p2][q * 4 + r][lane] + bias[och];
          if (mode == 2) {
            if (och >= 18) v = 1.f / (1.f + expf(-v));
          } else if (mode == 3) {
            v += b2f(resh[pixb * 64 + och]);
          }
          outF[((size_t)(n * O + och)) * HW + y * 128 + px] = v;
        }
      }
    }
  }
}

// ---------------------------------------------------------------------------
// Modulated deformable conv 3x3 via gather + MFMA (unchanged — validated).
// ---------------------------------------------------------------------------
__global__ __launch_bounds__(512) void deform_mf(
    const u16* __restrict__ xh, const float* __restrict__ offm,
    const u16* __restrict__ wpk, const float* __restrict__ bias,
    u16* __restrict__ outH) {
  __shared__ float s_off[27][128];
  __shared__ float s_red[4][2][16][64];
  const int tid = threadIdx.x;
  const int lane = tid & 63;
  const int w = tid >> 6;
  const int p2 = w >> 1;
  const int kh = w & 1;
  const int y = blockIdx.x;
  const int n = blockIdx.y;
  const int px = (p2 << 5) + (lane & 31);
  const int h = lane >> 5;

  for (int idx = tid; idx < 27 * 128; idx += 512) {
    int ch = idx >> 7, pp = idx & 127;
    s_off[ch][pp] = offm[((size_t)(n * 27 + ch) * 128 + y) * 128 + pp];
  }
  __syncthreads();

  f32x16 acc0, acc1;
#pragma unroll
  for (int i = 0; i < 16; ++i) { acc0[i] = 0.f; acc1[i] = 0.f; }

  const u16* xb = xh + ((size_t)n * HW) * 64;

#pragma unroll
  for (int kk = 0; kk < 5; ++kk) {
    if (kh && kk == 4) break;
    const int k = kh * 5 + kk;
    const int ky = k / 3 - 1, kx = k % 3 - 1;
    float dy = s_off[2 * k][px];
    float dx = s_off[2 * k + 1][px];
    float m = s_off[18 + k][px];
    float py = dy + (float)(y + ky);
    float pxf = dx + (float)(px + kx);
    float fy = floorf(py), fxx = floorf(pxf);
    float wy = py - fy, wx = pxf - fxx;
    int iy0 = (int)fy, ix0 = (int)fxx;
    bool vy0 = (unsigned)iy0 < 128u, vy1 = (unsigned)(iy0 + 1) < 128u;
    bool vx0 = (unsigned)ix0 < 128u, vx1 = (unsigned)(ix0 + 1) < 128u;
    float omwy = 1.f - wy, omwx = 1.f - wx;
    float f00 = (vy0 && vx0) ? omwy * omwx * m : 0.f;
    float f01 = (vy0 && vx1) ? omwy * wx * m : 0.f;
    float f10 = (vy1 && vx0) ? wy * omwx * m : 0.f;
    float f11 = (vy1 && vx1) ? wy * wx * m : 0.f;
    int y0c = min(max(iy0, 0), 127), y1c = min(max(iy0 + 1, 0), 127);
    int x0c = min(max(ix0, 0), 127), x1c = min(max(ix0 + 1, 0), 127);
    const u16* r00 = xb + ((size_t)(y0c * 128 + x0c)) * 64;
    const u16* r01 = xb + ((size_t)(y0c * 128 + x1c)) * 64;
    const u16* r10 = xb + ((size_t)(y1c * 128 + x0c)) * 64;
    const u16* r11 = xb + ((size_t)(y1c * 128 + x1c)) * 64;
#pragma unroll
    for (int ks = 0; ks < 4; ++ks) {
      const int co = ks * 16 + h * 8;
      U16B u00, u01, u10, u11;
      u00.u = *(const uint4*)(r00 + co);
      u01.u = *(const uint4*)(r01 + co);
      u10.u = *(const uint4*)(r10 + co);
      u11.u = *(const uint4*)(r11 + co);
      unsigned dw[4];
#pragma unroll
      for (int jj = 0; jj < 4; ++jj) {
        float s0 = f00 * b2f(u00.s[2 * jj]) + f01 * b2f(u01.s[2 * jj]) +
                   f10 * b2f(u10.s[2 * jj]) + f11 * b2f(u11.s[2 * jj]);
        float s1 = f00 * b2f(u00.s[2 * jj + 1]) + f01 * b2f(u01.s[2 * jj + 1]) +
                   f10 * b2f(u10.s[2 * jj + 1]) + f11 * b2f(u11.s[2 * jj + 1]);
        dw[jj] = (unsigned)f2b(s0) | ((unsigned)f2b(s1) << 16);
      }
      U16B bf;
      bf.u = make_uint4(dw[0], dw[1], dw[2], dw[3]);
      const u16* wp = wpk + ((size_t)((k * 4 + ks) * 2)) * 512 + lane * 8;
      U16B a0, a1;
      a0.u = *(const uint4*)wp;
      a1.u = *(const uint4*)(wp + 512);
      acc0 = __builtin_amdgcn_mfma_f32_32x32x16_bf16(a0.v, bf.v, acc0, 0, 0, 0);
      acc1 = __builtin_amdgcn_mfma_f32_32x32x16_bf16(a1.v, bf.v, acc1, 0, 0, 0);
    }
  }

  if (kh == 1) {
#pragma unroll
    for (int i = 0; i < 16; ++i) {
      s_red[p2][0][i][lane] = acc0[i];
      s_red[p2][1][i][lane] = acc1[i];
    }
  }
  __syncthreads();
  if (kh == 0) {
    const size_t pixb = (((size_t)(n * 128 + y)) * 128 + px) * 64;
#pragma unroll
    for (int ot = 0; ot < 2; ++ot) {
      f32x16 A = ot ? acc1 : acc0;
#pragma unroll
      for (int q = 0; q < 4; ++q) {
        int oo = ot * 32 + 8 * q + 4 * h;
        float v[4];
#pragma unroll
        for (int r = 0; r < 4; ++r)
          v[r] = A[q * 4 + r] + s_red[p2][ot][q * 4 + r][lane] + bias[oo + r];
        ushort4 hh;
        hh.x = f2b(v[0]); hh.y = f2b(v[1]); hh.z = f2b(v[2]); hh.w = f2b(v[3]);
        *(ushort4*)(outH + pixb + oo) = hh;
      }
    }
  }
}

// ---------------------------------------------------------------------------
extern "C" void kernel_launch(void* const* d_in, const int* in_sizes, int n_in,
                              void* d_out, int out_size, void* d_ws, size_t ws_size,
                              hipStream_t stream) {
  const float* xd = (const float*)d_in[0];
  const float* xl = (const float*)d_in[1];
  const float* xr = (const float*)d_in[2];
  const float* up_w = (const float*)d_in[3];
  const float* up_b = (const float*)d_in[4];
  const float* offl_w = (const float*)d_in[5];
  const float* offl_b = (const float*)d_in[6];
  const float* dl_w = (const float*)d_in[7];
  const float* dl_b = (const float*)d_in[8];
  const float* offr_w = (const float*)d_in[9];
  const float* offr_b = (const float*)d_in[10];
  const float* dr_w = (const float*)d_in[11];
  const float* dr_b = (const float*)d_in[12];
  const float* cv_w = (const float*)d_in[13];
  const float* cv_b = (const float*)d_in[14];
  const float* rb1_w1 = (const float*)d_in[15];
  const float* rb1_w2 = (const float*)d_in[16];
  const float* rb2_w1 = (const float*)d_in[17];
  const float* rb2_w2 = (const float*)d_in[18];
  const float* rb1_b1 = (const float*)d_in[19];
  const float* rb1_b2 = (const float*)d_in[20];
  const float* rb2_b1 = (const float*)d_in[21];
  const float* rb2_b2 = (const float*)d_in[22];

  float* ws = (float*)d_ws;
  float* ol = ws;                  // 884736
  float* orr = ws + 884736;        // 884736
  u16* hb = (u16*)(ws + 1769472);
  u16* xlh = hb;                   // 2097152 each
  u16* xrh = hb + 2097152;
  u16* xdph = hb + 4194304;
  u16* xl2h = hb + 6291456;
  u16* xr2h = hb + 8388608;
  u16* t0h = hb + 10485760;
  u16* t1h = hb + 12582912;
  u16* t2h = hb + 14680064;
  u16* t3h = hb + 16777216;
  u16* xdh = hb + 18874368;        // 1048576 (2*64*64*128)
  u16* wcv = hb + 19922944;        // 110592
  u16* wofl = hb + 20033536;       // 55296
  u16* wofr = hb + 20088832;       // 55296
  u16* wr1a = hb + 20144128;       // 36864
  u16* wr1b = hb + 20180992;
  u16* wr2a = hb + 20217856;
  u16* wr2b = hb + 20254720;
  u16* wdl = hb + 20291584;        // 36864
  u16* wdr = hb + 20328448;        // 36864
  u16* wup = hb + 20365312;        // 32768
  float* outp = (float*)d_out;

  hipLaunchKernelGGL(prep_kernel, dim3(1856), dim3(256), 0, stream,
                     dl_w, dr_w, up_w, cv_w, offl_w, offr_w, rb1_w1, rb1_w2,
                     rb2_w1, rb2_w2, wup, wdl, wdr, wcv, wofl, wofr, wr1a,
                     wr1b, wr2a, wr2b);
  hipLaunchKernelGGL(cvt_nhwc, dim3(128, 4), dim3(256), 0, stream,
                     xl, xr, xlh, xrh);
  hipLaunchKernelGGL(cvt_xd, dim3(64, 2), dim3(256), 0, stream,
                     xd, xdh);
  hipLaunchKernelGGL(upconv_mf, dim3(128, 2), dim3(512), 0, stream,
                     xdh, wup, up_b, xdph);
  hipLaunchKernelGGL(mfconv_d<3>, dim3(128, 1, 2), dim3(512), 0, stream,
                     xlh, xrh, xdph, wofl, offl_b, (const u16*)nullptr, ol,
                     (u16*)nullptr, 1, 27, 2);
  hipLaunchKernelGGL(deform_mf, dim3(128, 2), dim3(512), 0, stream,
                     xlh, ol, wdl, dl_b, xl2h);
  hipLaunchKernelGGL(mfconv_d<3>, dim3(128, 1, 2), dim3(512), 0, stream,
                     xl2h, xrh, xdph, wofr, offr_b, (const u16*)nullptr, orr,
                     (u16*)nullptr, 1, 27, 2);
  hipLaunchKernelGGL(deform_mf, dim3(128, 2), dim3(512), 0, stream,
                     xrh, orr, wdr, dr_b, xr2h);
  hipLaunchKernelGGL(mfconv_d<3>, dim3(128, 2, 2), dim3(512), 0, stream,
                     xl2h, xr2h, xdph, wcv, cv_b, (const u16*)nullptr,
                     (float*)nullptr, t0h, 2, 64, 1);
  hipLaunchKernelGGL(mfconv_d<1>, dim3(128, 2, 2), dim3(512), 0, stream,
                     t0h, (const u16*)nullptr, (const u16*)nullptr, wr1a,
                     rb1_b1, (const u16*)nullptr, (float*)nullptr, t1h,
                     2, 64, 1);
  hipLaunchKernelGGL(mfconv_d<1>, dim3(128, 2, 2), dim3(512), 0, stream,
                     t1h, (const u16*)nullptr, (const u16*)nullptr, wr1b,
                     rb1_b2, t0h, (float*)nullptr, t2h, 2, 64, 3);
  hipLaunchKernelGGL(mfconv_d<1>, dim3(128, 2, 2), dim3(512), 0, stream,
                     t2h, (const u16*)nullptr, (const u16*)nullptr, wr2a,
                     rb2_b1, (const u16*)nullptr, (float*)nullptr, t3h,
                     2, 64, 1);
  hipLaunchKernelGGL(mfconv_d<1>, dim3(128, 2, 2), dim3(512), 0, stream,
                     t3h, (const u16*)nullptr, (const u16*)nullptr, wr2b,
                     rb2_b2, t2h, outp, (u16*)nullptr, 2, 64, 3);
}

// Round 8
// 195.996 us; speedup vs baseline: 7.6827x; 1.0923x over previous
//
#include <hip/hip_runtime.h>
#include <math.h>

#define HW 16384

typedef unsigned short u16;
typedef __attribute__((ext_vector_type(8))) short short8;
typedef __attribute__((ext_vector_type(16))) float f32x16;

union U16B {
  uint4 u;
  short8 v;
  u16 s[8];
};

__device__ inline u16 f2b(float f) {
  unsigned u = __float_as_uint(f);
  u += 0x7FFF + ((u >> 16) & 1);
  return (u16)(u >> 16);
}
__device__ inline float b2f(u16 h) {
  return __uint_as_float(((unsigned)h) << 16);
}

// ---------------------------------------------------------------------------
// Weight packing helpers (bf16 per-lane MFMA A-fragments).
//  - 3x3 convs: wpk[((((s*3+ky)*3+kx)*4+ks)*OT+ot)*512 + lane*8 + j]
//  - deform:    wdk[((k*4+ks)*2+ot)*512 + lane*8 + j]
//  - upconv:    wup[((t*8+ks)*2+ot)*512 + lane*8 + j]  (Cin=128 -> ks 0..7)
// ---------------------------------------------------------------------------
__device__ inline u16 pack_frag(const float* __restrict__ w, int Cin, int O,
                                int OT, int d) {
  int j = d & 7;
  int lane = (d >> 3) & 63;
  int rest = d >> 9;
  int ot = rest % OT; rest /= OT;
  int ks = rest & 3; rest >>= 2;
  int kx = rest % 3; rest /= 3;
  int ky = rest % 3; int s = rest / 3;
  int och = ot * 32 + (lane & 31);
  int ch = s * 64 + ks * 16 + ((lane >> 5) << 3) + j;
  if (och >= O) return 0;
  return f2b(w[((size_t)och * Cin + ch) * 9 + ky * 3 + kx]);
}

__device__ inline u16 pack_def(const float* __restrict__ w, int d) {
  int j = d & 7;
  int lane = (d >> 3) & 63;
  int g = d >> 9;
  int ot = g & 1;
  int t = g >> 1;
  int ks = t & 3;
  int k = t >> 2;
  int och = ot * 32 + (lane & 31);
  int c = ks * 16 + ((lane >> 5) << 3) + j;
  return f2b(w[((size_t)och * 64 + c) * 9 + k]);
}

__device__ inline u16 pack_up(const float* __restrict__ w, int d) {
  int j = d & 7;
  int lane = (d >> 3) & 63;
  int g = d >> 9;
  int ot = g & 1;
  int rest = g >> 1;
  int ks = rest & 7;
  int t = rest >> 3;
  int och = ot * 32 + (lane & 31);
  int ci = ks * 16 + ((lane >> 5) << 3) + j;
  return f2b(w[((size_t)och * 128 + ci) * 4 + t]);
}

// ---------------------------------------------------------------------------
// setup_kernel = prep (weight packing) + cvt_nhwc (xl,xr) + cvt_xd, one launch.
// blocks [0,1856): prep; [1856,2368): cvt_nhwc; [2368,2496): cvt_xd.
// ---------------------------------------------------------------------------
__global__ __launch_bounds__(256) void setup_kernel(
    const float* __restrict__ dl_w, const float* __restrict__ dr_w,
    const float* __restrict__ up_w, const float* __restrict__ cv_w,
    const float* __restrict__ offl_w, const float* __restrict__ offr_w,
    const float* __restrict__ r1a, const float* __restrict__ r1b,
    const float* __restrict__ r2a, const float* __restrict__ r2b,
    u16* __restrict__ wup, u16* __restrict__ wdl, u16* __restrict__ wdr,
    u16* __restrict__ wcv, u16* __restrict__ wofl, u16* __restrict__ wofr,
    u16* __restrict__ wr1a, u16* __restrict__ wr1b,
    u16* __restrict__ wr2a, u16* __restrict__ wr2b,
    const float* __restrict__ xl, const float* __restrict__ xr,
    u16* __restrict__ xlh, u16* __restrict__ xrh,
    const float* __restrict__ xd, u16* __restrict__ xdh) {
  __shared__ float sT[8448];
  int tid = threadIdx.x;
  int b = blockIdx.x;
  if (b < 1856) {
    int d = b * 256 + tid;
    if (d < 32768) { wup[d] = pack_up(up_w, d); return; }
    d -= 32768;
    if (d < 36864) { wdl[d] = pack_def(dl_w, d); return; }
    d -= 36864;
    if (d < 36864) { wdr[d] = pack_def(dr_w, d); return; }
    d -= 36864;
    if (d < 110592) { wcv[d] = pack_frag(cv_w, 192, 64, 2, d); return; }
    d -= 110592;
    if (d < 55296) { wofl[d] = pack_frag(offl_w, 192, 27, 1, d); return; }
    d -= 55296;
    if (d < 55296) { wofr[d] = pack_frag(offr_w, 192, 27, 1, d); return; }
    d -= 55296;
    if (d < 36864) { wr1a[d] = pack_frag(r1a, 64, 64, 2, d); return; }
    d -= 36864;
    if (d < 36864) { wr1b[d] = pack_frag(r1b, 64, 64, 2, d); return; }
    d -= 36864;
    if (d < 36864) { wr2a[d] = pack_frag(r2a, 64, 64, 2, d); return; }
    d -= 36864;
    if (d < 36864) { wr2b[d] = pack_frag(r2b, 64, 64, 2, d); return; }
    return;
  }
  b -= 1856;
  if (b < 512) {
    // cvt_nhwc: y = b&127, pid = b>>7
    int y = b & 127;
    int pid = b >> 7;
    const float* src = (pid >> 1) ? xr : xl;
    u16* dst = (pid >> 1) ? xrh : xlh;
    int n = pid & 1;
#pragma unroll
    for (int i = 0; i < 8; ++i) {
      int q = tid + i * 256;
      int ch = q >> 5, pxq = q & 31;
      float4 v = *(const float4*)(src + ((size_t)(n * 64 + ch)) * HW + y * 128 + pxq * 4);
      *(float4*)&sT[ch * 132 + pxq * 4] = v;
    }
    __syncthreads();
    int px = tid >> 1, half = tid & 1;
    u16* op = dst + (((size_t)(n * 128 + y)) * 128 + px) * 64 + half * 32;
#pragma unroll
    for (int c = 0; c < 4; ++c) {
      uint4 v;
      int ob = (half * 32 + c * 8);
      v.x = (unsigned)f2b(sT[(ob + 0) * 132 + px]) | ((unsigned)f2b(sT[(ob + 1) * 132 + px]) << 16);
      v.y = (unsigned)f2b(sT[(ob + 2) * 132 + px]) | ((unsigned)f2b(sT[(ob + 3) * 132 + px]) << 16);
      v.z = (unsigned)f2b(sT[(ob + 4) * 132 + px]) | ((unsigned)f2b(sT[(ob + 5) * 132 + px]) << 16);
      v.w = (unsigned)f2b(sT[(ob + 6) * 132 + px]) | ((unsigned)f2b(sT[(ob + 7) * 132 + px]) << 16);
      *(uint4*)(op + c * 8) = v;
    }
    return;
  }
  b -= 512;
  {
    // cvt_xd: r = b&63, n = b>>6
    int r = b & 63;
    int n = b >> 6;
#pragma unroll
    for (int i = 0; i < 8; ++i) {
      int q = tid + i * 256;
      int ch = q >> 4, col4 = q & 15;
      float4 v = *(const float4*)(xd + ((size_t)(n * 128 + ch) * 64 + r) * 64 + col4 * 4);
      *(float4*)&sT[ch * 66 + col4 * 4] = v;
    }
    __syncthreads();
#pragma unroll
    for (int i = 0; i < 4; ++i) {
      int q = tid + i * 256;
      int col = q >> 4, cho = q & 15;
      uint4 v;
      int cb = cho * 8;
      v.x = (unsigned)f2b(sT[(cb + 0) * 66 + col]) | ((unsigned)f2b(sT[(cb + 1) * 66 + col]) << 16);
      v.y = (unsigned)f2b(sT[(cb + 2) * 66 + col]) | ((unsigned)f2b(sT[(cb + 3) * 66 + col]) << 16);
      v.z = (unsigned)f2b(sT[(cb + 4) * 66 + col]) | ((unsigned)f2b(sT[(cb + 5) * 66 + col]) << 16);
      v.w = (unsigned)f2b(sT[(cb + 6) * 66 + col]) | ((unsigned)f2b(sT[(cb + 7) * 66 + col]) << 16);
      *(uint4*)(xdh + (((size_t)(n * 64 + r)) * 64 + col) * 128 + cb) = v;
    }
  }
}

// ---------------------------------------------------------------------------
// Fused nearest-x2 upsample + 2x2 conv + zero-pad via gather + MFMA.
// (unchanged — validated)
// ---------------------------------------------------------------------------
__global__ __launch_bounds__(512) void upconv_mf(
    const u16* __restrict__ xdh, const u16* __restrict__ wup,
    const float* __restrict__ bias, u16* __restrict__ outH) {
  __shared__ float s_red[4][2][16][64];
  const int tid = threadIdx.x;
  const int lane = tid & 63;
  const int w = tid >> 6;
  const int p2 = w >> 1;
  const int th = w & 1;
  const int y = blockIdx.x;
  const int n = blockIdx.y;
  const int px = (p2 << 5) + (lane & 31);
  const int h = lane >> 5;

  f32x16 acc0, acc1;
#pragma unroll
  for (int i = 0; i < 16; ++i) { acc0[i] = 0.f; acc1[i] = 0.f; }

  const u16* xb = xdh + ((size_t)n * 64 * 64) * 128;

#pragma unroll
  for (int tt = 0; tt < 2; ++tt) {
    const int t = th * 2 + tt;
    const int ty = t >> 1, tx = t & 1;
    const int row = min((y + ty) >> 1, 63);
    const int col = min((px + tx) >> 1, 63);
    const u16* src = xb + ((size_t)(row * 64 + col)) * 128;
#pragma unroll
    for (int ks = 0; ks < 8; ++ks) {
      U16B bf;
      bf.u = *(const uint4*)(src + ks * 16 + h * 8);
      const u16* wp = wup + ((size_t)((t * 8 + ks) * 2)) * 512 + lane * 8;
      U16B a0, a1;
      a0.u = *(const uint4*)wp;
      a1.u = *(const uint4*)(wp + 512);
      acc0 = __builtin_amdgcn_mfma_f32_32x32x16_bf16(a0.v, bf.v, acc0, 0, 0, 0);
      acc1 = __builtin_amdgcn_mfma_f32_32x32x16_bf16(a1.v, bf.v, acc1, 0, 0, 0);
    }
  }

  if (th == 1) {
#pragma unroll
    for (int i = 0; i < 16; ++i) {
      s_red[p2][0][i][lane] = acc0[i];
      s_red[p2][1][i][lane] = acc1[i];
    }
  }
  __syncthreads();
  if (th == 0) {
    const bool zero = (y == 127) || (px == 127);
    const size_t pixb = (((size_t)(n * 128 + y)) * 128 + px) * 64;
#pragma unroll
    for (int ot = 0; ot < 2; ++ot) {
      f32x16 A = ot ? acc1 : acc0;
#pragma unroll
      for (int q = 0; q < 4; ++q) {
        int oo = ot * 32 + 8 * q + 4 * h;
        float v[4];
#pragma unroll
        for (int r = 0; r < 4; ++r)
          v[r] = zero ? 0.f : (A[q * 4 + r] + s_red[p2][ot][q * 4 + r][lane] + bias[oo + r]);
        ushort4 hh;
        hh.x = f2b(v[0]); hh.y = f2b(v[1]); hh.z = f2b(v[2]); hh.w = f2b(v[3]);
        *(ushort4*)(outH + pixb + oo) = hh;
      }
    }
  }
}

// ---------------------------------------------------------------------------
// MFMA 3x3 conv, pad=1, direct-global-load, half-row blocks, 4-way ks split.
// Block = 64 px x 32 och: 512 thr = 8 waves = 2 px-tiles x 4 ks-quarters.
// grid = (256 rowhalves, OT, n). 3-way LDS combine by kq==0 waves.
// mode: 1=relu (bf16 out), 3=+residual (bf16 out, or fp32 NCHW if outF)
// ---------------------------------------------------------------------------
template <int NSEG>
__global__ __launch_bounds__(512) void mfconv_d(
    const u16* __restrict__ in0, const u16* __restrict__ in1,
    const u16* __restrict__ in2, const u16* __restrict__ wpk,
    const float* __restrict__ bias, const u16* __restrict__ resh,
    float* __restrict__ outF, u16* __restrict__ outH,
    int OT, int O, int mode) {
  __shared__ float s_red[2][3][16][64];
  const int tid = threadIdx.x;
  const int lane = tid & 63;
  const int w = tid >> 6;
  const int p2 = w >> 2;      // px tile (0..1)
  const int kq = w & 3;       // ks quarter (0..3)
  const int y = blockIdx.x >> 1;
  const int xh0 = (blockIdx.x & 1) << 6;
  const int ot = blockIdx.y;
  const int n = blockIdx.z;
  const int px = xh0 + (p2 << 5) + (lane & 31);
  const int h = lane >> 5;

  f32x16 acc;
#pragma unroll
  for (int i = 0; i < 16; ++i) acc[i] = 0.f;

#pragma unroll
  for (int s = 0; s < NSEG; ++s) {
    const u16* sp = (s == 0) ? in0 : ((s == 1) ? in1 : in2);
    const u16* bn = sp + ((size_t)n * 128) * 128 * 64;
#pragma unroll
    for (int ky = 0; ky < 3; ++ky) {
      int r = y + ky - 1;
      if ((unsigned)r >= 128u) continue;
      const u16* rp = bn + (size_t)r * (128 * 64);
#pragma unroll
      for (int kx = 0; kx < 3; ++kx) {
        int col = px + kx - 1;
        bool valid = (unsigned)col < 128u;
        int colc = min(max(col, 0), 127);
        const u16* pp = rp + (size_t)colc * 64 + h * 8;
        U16B bf;
        bf.u = *(const uint4*)(pp + kq * 16);
        if (!valid) bf.u = make_uint4(0, 0, 0, 0);
        U16B a;
        a.u = *(const uint4*)(wpk +
              ((size_t)((((s * 3 + ky) * 3 + kx) * 4 + kq) * OT + ot)) * 512 +
              lane * 8);
        acc = __builtin_amdgcn_mfma_f32_32x32x16_bf16(a.v, bf.v, acc, 0, 0, 0);
      }
    }
  }

  if (kq != 0) {
#pragma unroll
    for (int i = 0; i < 16; ++i) s_red[p2][kq - 1][i][lane] = acc[i];
  }
  __syncthreads();
  if (kq == 0) {
#pragma unroll
    for (int i = 0; i < 16; ++i)
      acc[i] += s_red[p2][0][i][lane] + s_red[p2][1][i][lane] + s_red[p2][2][i][lane];
    const size_t pixb = ((size_t)(n * 128 + y)) * 128 + px;
    if (outH) {
#pragma unroll
      for (int q = 0; q < 4; ++q) {
        int oo = ot * 32 + 8 * q + 4 * h;
        float v[4];
#pragma unroll
        for (int r = 0; r < 4; ++r) v[r] = acc[q * 4 + r] + bias[oo + r];
        if (mode == 1) {
#pragma unroll
          for (int r = 0; r < 4; ++r) v[r] = fmaxf(v[r], 0.f);
        } else if (mode == 3) {
          ushort4 rv = *(const ushort4*)(resh + pixb * 64 + oo);
          v[0] += b2f(rv.x); v[1] += b2f(rv.y); v[2] += b2f(rv.z); v[3] += b2f(rv.w);
        }
        ushort4 hh;
        hh.x = f2b(v[0]); hh.y = f2b(v[1]); hh.z = f2b(v[2]); hh.w = f2b(v[3]);
        *(ushort4*)(outH + pixb * 64 + oo) = hh;
      }
    } else {
#pragma unroll
      for (int q = 0; q < 4; ++q) {
        int oo = ot * 32 + 8 * q + 4 * h;
#pragma unroll
        for (int r = 0; r < 4; ++r) {
          int och = oo + r;
          if (och >= O) continue;
          float v = acc[q * 4 + r] + bias[och];
          if (mode == 3) v += b2f(resh[pixb * 64 + och]);
          outF[((size_t)(n * O + och)) * HW + y * 128 + px] = v;
        }
      }
    }
  }
}

// ---------------------------------------------------------------------------
// Fused {offset conv (Cin=192, O=27) -> s_off} + {modulated deformable conv}.
// Block = one row, 512 thr = 8 waves = 4 px-tiles x 2 halves.
// Phase 1: offset conv via direct-load MFMA, kh = ks-half; reduce via LDS,
//          apply sigmoid to mask ch >= 18, write s_off[27][128].
// Phase 2: gather+blend+MFMA deform (validated deform_mf body).
// ---------------------------------------------------------------------------
__global__ __launch_bounds__(512) void deform_fused(
    const u16* __restrict__ in0, const u16* __restrict__ in1,
    const u16* __restrict__ in2, const u16* __restrict__ woff,
    const float* __restrict__ boff, const u16* __restrict__ xh,
    const u16* __restrict__ wdef, const float* __restrict__ bdef,
    u16* __restrict__ outH) {
  __shared__ float s_off[27][128];
  __shared__ float s_red[4][2][16][64];
  const int tid = threadIdx.x;
  const int lane = tid & 63;
  const int w = tid >> 6;
  const int p2 = w >> 1;
  const int kh = w & 1;
  const int y = blockIdx.x;
  const int n = blockIdx.y;
  const int px = (p2 << 5) + (lane & 31);
  const int h = lane >> 5;

  // ---- Phase 1: offset conv ----
  {
    f32x16 acc;
#pragma unroll
    for (int i = 0; i < 16; ++i) acc[i] = 0.f;
#pragma unroll
    for (int s = 0; s < 3; ++s) {
      const u16* sp = (s == 0) ? in0 : ((s == 1) ? in1 : in2);
      const u16* bn = sp + ((size_t)n * 128) * 128 * 64;
#pragma unroll
      for (int ky = 0; ky < 3; ++ky) {
        int r = y + ky - 1;
        if ((unsigned)r >= 128u) continue;
        const u16* rp = bn + (size_t)r * (128 * 64);
#pragma unroll
        for (int kx = 0; kx < 3; ++kx) {
          int col = px + kx - 1;
          bool valid = (unsigned)col < 128u;
          int colc = min(max(col, 0), 127);
          const u16* pp = rp + (size_t)colc * 64 + h * 8;
#pragma unroll
          for (int k2 = 0; k2 < 2; ++k2) {
            int ks = kh * 2 + k2;
            U16B bf;
            bf.u = *(const uint4*)(pp + ks * 16);
            if (!valid) bf.u = make_uint4(0, 0, 0, 0);
            U16B a;
            a.u = *(const uint4*)(woff +
                  ((size_t)(((s * 3 + ky) * 3 + kx) * 4 + ks)) * 512 + lane * 8);
            acc = __builtin_amdgcn_mfma_f32_32x32x16_bf16(a.v, bf.v, acc, 0, 0, 0);
          }
        }
      }
    }
    if (kh == 1) {
#pragma unroll
      for (int i = 0; i < 16; ++i) s_red[p2][0][i][lane] = acc[i];
    }
    __syncthreads();
    if (kh == 0) {
#pragma unroll
      for (int q = 0; q < 4; ++q) {
#pragma unroll
        for (int r = 0; r < 4; ++r) {
          int och = 8 * q + 4 * h + r;
          if (och < 27) {
            float v = acc[q * 4 + r] + s_red[p2][0][q * 4 + r][lane] + boff[och];
            if (och >= 18) v = 1.f / (1.f + expf(-v));
            s_off[och][px] = v;
          }
        }
      }
    }
  }
  __syncthreads();

  // ---- Phase 2: deform gather + GEMM ----
  f32x16 acc0, acc1;
#pragma unroll
  for (int i = 0; i < 16; ++i) { acc0[i] = 0.f; acc1[i] = 0.f; }

  const u16* xb = xh + ((size_t)n * HW) * 64;

#pragma unroll
  for (int kk = 0; kk < 5; ++kk) {
    if (kh && kk == 4) break;
    const int k = kh * 5 + kk;
    const int ky = k / 3 - 1, kx = k % 3 - 1;
    float dy = s_off[2 * k][px];
    float dx = s_off[2 * k + 1][px];
    float m = s_off[18 + k][px];
    float py = dy + (float)(y + ky);
    float pxf = dx + (float)(px + kx);
    float fy = floorf(py), fxx = floorf(pxf);
    float wy = py - fy, wx = pxf - fxx;
    int iy0 = (int)fy, ix0 = (int)fxx;
    bool vy0 = (unsigned)iy0 < 128u, vy1 = (unsigned)(iy0 + 1) < 128u;
    bool vx0 = (unsigned)ix0 < 128u, vx1 = (unsigned)(ix0 + 1) < 128u;
    float omwy = 1.f - wy, omwx = 1.f - wx;
    float f00 = (vy0 && vx0) ? omwy * omwx * m : 0.f;
    float f01 = (vy0 && vx1) ? omwy * wx * m : 0.f;
    float f10 = (vy1 && vx0) ? wy * omwx * m : 0.f;
    float f11 = (vy1 && vx1) ? wy * wx * m : 0.f;
    int y0c = min(max(iy0, 0), 127), y1c = min(max(iy0 + 1, 0), 127);
    int x0c = min(max(ix0, 0), 127), x1c = min(max(ix0 + 1, 0), 127);
    const u16* r00 = xb + ((size_t)(y0c * 128 + x0c)) * 64;
    const u16* r01 = xb + ((size_t)(y0c * 128 + x1c)) * 64;
    const u16* r10 = xb + ((size_t)(y1c * 128 + x0c)) * 64;
    const u16* r11 = xb + ((size_t)(y1c * 128 + x1c)) * 64;
#pragma unroll
    for (int ks = 0; ks < 4; ++ks) {
      const int co = ks * 16 + h * 8;
      U16B u00, u01, u10, u11;
      u00.u = *(const uint4*)(r00 + co);
      u01.u = *(const uint4*)(r01 + co);
      u10.u = *(const uint4*)(r10 + co);
      u11.u = *(const uint4*)(r11 + co);
      unsigned dw[4];
#pragma unroll
      for (int jj = 0; jj < 4; ++jj) {
        float s0 = f00 * b2f(u00.s[2 * jj]) + f01 * b2f(u01.s[2 * jj]) +
                   f10 * b2f(u10.s[2 * jj]) + f11 * b2f(u11.s[2 * jj]);
        float s1 = f00 * b2f(u00.s[2 * jj + 1]) + f01 * b2f(u01.s[2 * jj + 1]) +
                   f10 * b2f(u10.s[2 * jj + 1]) + f11 * b2f(u11.s[2 * jj + 1]);
        dw[jj] = (unsigned)f2b(s0) | ((unsigned)f2b(s1) << 16);
      }
      U16B bf;
      bf.u = make_uint4(dw[0], dw[1], dw[2], dw[3]);
      const u16* wp = wdef + ((size_t)((k * 4 + ks) * 2)) * 512 + lane * 8;
      U16B a0, a1;
      a0.u = *(const uint4*)wp;
      a1.u = *(const uint4*)(wp + 512);
      acc0 = __builtin_amdgcn_mfma_f32_32x32x16_bf16(a0.v, bf.v, acc0, 0, 0, 0);
      acc1 = __builtin_amdgcn_mfma_f32_32x32x16_bf16(a1.v, bf.v, acc1, 0, 0, 0);
    }
  }

  if (kh == 1) {
#pragma unroll
    for (int i = 0; i < 16; ++i) {
      s_red[p2][0][i][lane] = acc0[i];
      s_red[p2][1][i][lane] = acc1[i];
    }
  }
  __syncthreads();
  if (kh == 0) {
    const size_t pixb = (((size_t)(n * 128 + y)) * 128 + px) * 64;
#pragma unroll
    for (int ot = 0; ot < 2; ++ot) {
      f32x16 A = ot ? acc1 : acc0;
#pragma unroll
      for (int q = 0; q < 4; ++q) {
        int oo = ot * 32 + 8 * q + 4 * h;
        float v[4];
#pragma unroll
        for (int r = 0; r < 4; ++r)
          v[r] = A[q * 4 + r] + s_red[p2][ot][q * 4 + r][lane] + bdef[oo + r];
        ushort4 hh;
        hh.x = f2b(v[0]); hh.y = f2b(v[1]); hh.z = f2b(v[2]); hh.w = f2b(v[3]);
        *(ushort4*)(outH + pixb + oo) = hh;
      }
    }
  }
}

// ---------------------------------------------------------------------------
extern "C" void kernel_launch(void* const* d_in, const int* in_sizes, int n_in,
                              void* d_out, int out_size, void* d_ws, size_t ws_size,
                              hipStream_t stream) {
  const float* xd = (const float*)d_in[0];
  const float* xl = (const float*)d_in[1];
  const float* xr = (const float*)d_in[2];
  const float* up_w = (const float*)d_in[3];
  const float* up_b = (const float*)d_in[4];
  const float* offl_w = (const float*)d_in[5];
  const float* offl_b = (const float*)d_in[6];
  const float* dl_w = (const float*)d_in[7];
  const float* dl_b = (const float*)d_in[8];
  const float* offr_w = (const float*)d_in[9];
  const float* offr_b = (const float*)d_in[10];
  const float* dr_w = (const float*)d_in[11];
  const float* dr_b = (const float*)d_in[12];
  const float* cv_w = (const float*)d_in[13];
  const float* cv_b = (const float*)d_in[14];
  const float* rb1_w1 = (const float*)d_in[15];
  const float* rb1_w2 = (const float*)d_in[16];
  const float* rb2_w1 = (const float*)d_in[17];
  const float* rb2_w2 = (const float*)d_in[18];
  const float* rb1_b1 = (const float*)d_in[19];
  const float* rb1_b2 = (const float*)d_in[20];
  const float* rb2_b1 = (const float*)d_in[21];
  const float* rb2_b2 = (const float*)d_in[22];

  float* ws = (float*)d_ws;
  u16* hb = (u16*)(ws + 1769472);
  u16* xlh = hb;                   // 2097152 each
  u16* xrh = hb + 2097152;
  u16* xdph = hb + 4194304;
  u16* xl2h = hb + 6291456;
  u16* xr2h = hb + 8388608;
  u16* t0h = hb + 10485760;
  u16* t1h = hb + 12582912;
  u16* t2h = hb + 14680064;
  u16* t3h = hb + 16777216;
  u16* xdh = hb + 18874368;        // 1048576 (2*64*64*128)
  u16* wcv = hb + 19922944;        // 110592
  u16* wofl = hb + 20033536;       // 55296
  u16* wofr = hb + 20088832;       // 55296
  u16* wr1a = hb + 20144128;       // 36864
  u16* wr1b = hb + 20180992;
  u16* wr2a = hb + 20217856;
  u16* wr2b = hb + 20254720;
  u16* wdl = hb + 20291584;        // 36864
  u16* wdr = hb + 20328448;        // 36864
  u16* wup = hb + 20365312;        // 32768
  float* outp = (float*)d_out;

  hipLaunchKernelGGL(setup_kernel, dim3(2496), dim3(256), 0, stream,
                     dl_w, dr_w, up_w, cv_w, offl_w, offr_w, rb1_w1, rb1_w2,
                     rb2_w1, rb2_w2, wup, wdl, wdr, wcv, wofl, wofr, wr1a,
                     wr1b, wr2a, wr2b, xl, xr, xlh, xrh, xd, xdh);
  hipLaunchKernelGGL(upconv_mf, dim3(128, 2), dim3(512), 0, stream,
                     xdh, wup, up_b, xdph);
  hipLaunchKernelGGL(deform_fused, dim3(128, 2), dim3(512), 0, stream,
                     xlh, xrh, xdph, wofl, offl_b, xlh, wdl, dl_b, xl2h);
  hipLaunchKernelGGL(deform_fused, dim3(128, 2), dim3(512), 0, stream,
                     xl2h, xrh, xdph, wofr, offr_b, xrh, wdr, dr_b, xr2h);
  hipLaunchKernelGGL(mfconv_d<3>, dim3(256, 2, 2), dim3(512), 0, stream,
                     xl2h, xr2h, xdph, wcv, cv_b, (const u16*)nullptr,
                     (float*)nullptr, t0h, 2, 64, 1);
  hipLaunchKernelGGL(mfconv_d<1>, dim3(256, 2, 2), dim3(512), 0, stream,
                     t0h, (const u16*)nullptr, (const u16*)nullptr, wr1a,
                     rb1_b1, (const u16*)nullptr, (float*)nullptr, t1h,
                     2, 64, 1);
  hipLaunchKernelGGL(mfconv_d<1>, dim3(256, 2, 2), dim3(512), 0, stream,
                     t1h, (const u16*)nullptr, (const u16*)nullptr, wr1b,
                     rb1_b2, t0h, (float*)nullptr, t2h, 2, 64, 3);
  hipLaunchKernelGGL(mfconv_d<1>, dim3(256, 2, 2), dim3(512), 0, stream,
                     t2h, (const u16*)nullptr, (const u16*)nullptr, wr2a,
                     rb2_b1, (const u16*)nullptr, (float*)nullptr, t3h,
                     2, 64, 1);
  hipLaunchKernelGGL(mfconv_d<1>, dim3(256, 2, 2), dim3(512), 0, stream,
                     t3h, (const u16*)nullptr, (const u16*)nullptr, wr2b,
                     rb2_b2, t2h, outp, (u16*)nullptr, 2, 64, 3);
}